// Round 7
// baseline (34883.652 us; speedup 1.0000x reference)
//
#include <hip/hip_runtime.h>
#include <hip/hip_bf16.h>

#define TT 2048
#define BB 256
#define HH 128
#define UDIM 16
#define YDIM 16
#define ZDIM 32
#define H3 384

typedef __hip_bfloat16 bf16;

constexpr int clog2(int x) { return x <= 1 ? 0 : 1 + clog2(x >> 1); }

// ---------------------------------------------------------------------------
// Register-weight linear stage (phi_u + head). Mapping (M,K,O; O*(M/2)=512,
// F=K/O): thread T owns rows jb=T&(M/2-1), jb+M/2, col-chunk o=T>>log2(M/2).
// ---------------------------------------------------------------------------
template <int M_, int K_, int O_, bool RELU_>
__device__ __forceinline__ void rstage(const float* __restrict__ wfrag,
                                       const float* __restrict__ xin, int XS,
                                       float* __restrict__ ps,
                                       const float* __restrict__ bias,
                                       float* __restrict__ outb)
{
    constexpr int F = K_ / O_;
    const int T = threadIdx.x;
    const int jb = T & (M_ / 2 - 1);
    const int o  = T >> clog2(M_ / 2);
#pragma unroll
    for (int r = 0; r < 8; ++r) {
        float a0 = 0.f, a1 = 0.f;
#pragma unroll
        for (int g = 0; g < F; g += 4) {
            const float4 xv = *reinterpret_cast<const float4*>(&xin[r * XS + o * F + g]);
            a0 += xv.x * wfrag[g]     + xv.y * wfrag[g + 1]
                + xv.z * wfrag[g + 2] + xv.w * wfrag[g + 3];
            a1 += xv.x * wfrag[F + g]     + xv.y * wfrag[F + g + 1]
                + xv.z * wfrag[F + g + 2] + xv.w * wfrag[F + g + 3];
        }
        ps[r * 1024 + o * M_ + jb]           = a0;
        ps[r * 1024 + o * M_ + jb + M_ / 2]  = a1;
    }
    __syncthreads();
    for (int oi = T; oi < 8 * M_; oi += 512) {
        const int r = oi >> clog2(M_);
        const int j = oi & (M_ - 1);
        float s = bias[j];
#pragma unroll
        for (int o2 = 0; o2 < O_; ++o2) s += ps[r * 1024 + o2 * M_ + j];
        if (RELU_) s = fmaxf(s, 0.f);
        outb[r * M_ + j] = s;
    }
    __syncthreads();
}

template <int M_, int K_, int O_>
__device__ __forceinline__ void loadw(float* __restrict__ wfrag, const float* __restrict__ Wg)
{
    constexpr int F = K_ / O_;
    const int T = threadIdx.x;
    const int jb = T & (M_ / 2 - 1);
    const int o  = T >> clog2(M_ / 2);
#pragma unroll
    for (int h = 0; h < 2; ++h)
#pragma unroll
        for (int g = 0; g < F; g += 4)
            *reinterpret_cast<float4*>(&wfrag[h * F + g]) =
                *reinterpret_cast<const float4*>(&Wg[(jb + h * (M_ / 2)) * K_ + o * F + g]);
}

// ---------------------------------------------------------------------------
// phi_u (unchanged from round 6): register weights, persistent 512 blocks.
// ---------------------------------------------------------------------------
__global__ __launch_bounds__(512, 2) void phi_u_kernel(
    const float* __restrict__ u, const float* __restrict__ w1, const float* __restrict__ b1,
    const float* __restrict__ w2, const float* __restrict__ b2,
    bf16* __restrict__ pu, int s0, int nrows)
{
    __shared__ __align__(16) float ps[8192];
    __shared__ __align__(16) float xc[8 * 16];
    __shared__ __align__(16) float bP[8 * 128];
    __shared__ __align__(16) float bias_l[256];
    const int T = threadIdx.x;
    if (T < 128) { bias_l[T] = b1[T]; bias_l[128 + T] = b2[T]; }
    const int jb = T & 63, o = T >> 6;
    float wa[4];
    wa[0] = w1[jb * 16 + o * 2];        wa[1] = w1[jb * 16 + o * 2 + 1];
    wa[2] = w1[(jb + 64) * 16 + o * 2]; wa[3] = w1[(jb + 64) * 16 + o * 2 + 1];
    float wb[32]; loadw<128, 128, 8>(wb, w2);
    __syncthreads();

    for (int tile = blockIdx.x; tile < nrows / 32; tile += gridDim.x) {
        const int n0 = tile * 32;
        const int b  = s0 + (n0 >> 11);
        const int t0 = n0 & (TT - 1);
#pragma unroll 1
        for (int rb = 0; rb < 4; ++rb) {
            if (T < 128) {
                const int r = T & 7, c = T >> 3;
                xc[r * 16 + c] = u[((size_t)b * UDIM + c) * TT + t0 + rb * 8 + r];
            }
            __syncthreads();
#pragma unroll
            for (int r = 0; r < 8; ++r) {
                const float x0 = xc[r * 16 + o * 2], x1 = xc[r * 16 + o * 2 + 1];
                ps[r * 1024 + o * 128 + jb]      = x0 * wa[0] + x1 * wa[1];
                ps[r * 1024 + o * 128 + jb + 64] = x0 * wa[2] + x1 * wa[3];
            }
            __syncthreads();
            for (int oi = T; oi < 8 * 128; oi += 512) {
                const int r = oi >> 7, j = oi & 127;
                float s = bias_l[j];
#pragma unroll
                for (int o2 = 0; o2 < 8; ++o2) s += ps[r * 1024 + o2 * 128 + j];
                bP[r * 128 + j] = fmaxf(s, 0.f);
            }
            __syncthreads();
            rstage<128, 128, 8, false>(wb, bP, 128, ps, bias_l + 128, bP);
            const int row0 = n0 + rb * 8;
            for (int oi = T; oi < 8 * 128; oi += 512) {
                const int r = oi >> 7, j = oi & 127;
                pu[(size_t)(row0 + r) * HH + j] = __float2bfloat16(bP[r * 128 + j]);
            }
            __syncthreads();
        }
    }
}

// ---------------------------------------------------------------------------
// Fused 2-layer GRU, one block/sample, 1024 threads. One-step skew:
// threads 0-511 = layer 0 at step s; threads 512-1023 = layer 1 at step s-1.
// Per layer: 3072 tasks (2 mats x 384 rows x 4 k-slices of 32); thread
// (g=t>>6 -> m=g>>2,o=g&3; u=t&63) owns rows 6u..6u+5 of matrix m, slice o:
// 8 broadcast b128 reads feed 192 FMAs. Partials ps[layer][(m*384+row)*5+o]
// (stride 5: gate-phase scalar reads bank-free, 5 coprime 32).
// L0 output -> x1[2][H] LDS double buffer (layer-1 input); h0traj never
// touches global. hlast[tau] = L1 state ENTERING step tau (pre-update reg).
// ---------------------------------------------------------------------------
__global__ __launch_bounds__(1024) void gru_fused_kernel(
    const bf16* __restrict__ pu_in,   // (C*T, H)
    const float* __restrict__ wih,    // (L, 3H, H)
    const float* __restrict__ whh,    // (L, 3H, H)
    const float* __restrict__ h0_g,   // (L, B, H)
    bf16* __restrict__ hlast,         // (C*T, H)
    int s0)
{
    const int tid = threadIdx.x;
    const int layer = tid >> 9;       // wave-uniform (waves 0-7 / 8-15)
    const int t = tid & 511;
    __shared__ __align__(16) float x0[HH];
    __shared__ __align__(16) float h0s[HH];
    __shared__ __align__(16) float x1[2][HH];
    __shared__ __align__(16) float h1s[HH];
    __shared__ __align__(16) float ps[2 * 3840];

    const int g = t >> 6;             // wave-uniform
    const int m = g >> 2, o = g & 3;
    const int u = t & 63;
    const float* Wmat = (m == 0 ? wih : whh) + (size_t)layer * H3 * HH;
    float w[6][32];
#pragma unroll
    for (int i = 0; i < 6; ++i)
#pragma unroll
        for (int k = 0; k < 32; k += 4)
            *reinterpret_cast<float4*>(&w[i][k]) =
                *reinterpret_cast<const float4*>(&Wmat[(6 * u + i) * HH + o * 32 + k]);
    float* psL = ps + layer * 3840;
    const int psb = (m * 384 + 6 * u) * 5 + o;

    const bf16* xb = pu_in + (size_t)blockIdx.x * TT * HH;
    bf16* ob = hlast + (size_t)blockIdx.x * TT * HH;

    float hreg = 0.f;                 // L0 state on tid<128; L1 state on tid 512-639
    if (tid < HH) {
        hreg = h0_g[(size_t)(s0 + blockIdx.x) * HH + tid];
        h0s[tid] = hreg;
        x0[tid] = __bfloat162float(xb[tid]);
    } else if (tid >= 512 && tid < 512 + HH) {
        const int j = tid - 512;
        hreg = h0_g[((size_t)BB + s0 + blockIdx.x) * HH + j];
        h1s[j] = hreg;
    }
    __syncthreads();

#pragma unroll 1
    for (int s = 0; s <= TT; ++s) {
        const bool act = layer == 0 ? (s < TT) : (s >= 1);
        float xnext = 0.f;
        if (tid < HH && s + 1 < TT)
            xnext = __bfloat162float(xb[(size_t)(s + 1) * HH + tid]);   // prefetch
        if (act) {
            const float* vp;
            if (layer == 0) vp = (m == 0 ? x0 : h0s) + o * 32;
            else            vp = (m == 0 ? x1[(s + 1) & 1] : h1s) + o * 32;
            float a0 = 0.f, a1 = 0.f, a2 = 0.f, a3 = 0.f, a4 = 0.f, a5 = 0.f;
#pragma unroll
            for (int k = 0; k < 32; k += 4) {
                const float4 v = *reinterpret_cast<const float4*>(&vp[k]);
                a0 += v.x * w[0][k] + v.y * w[0][k + 1] + v.z * w[0][k + 2] + v.w * w[0][k + 3];
                a1 += v.x * w[1][k] + v.y * w[1][k + 1] + v.z * w[1][k + 2] + v.w * w[1][k + 3];
                a2 += v.x * w[2][k] + v.y * w[2][k + 1] + v.z * w[2][k + 2] + v.w * w[2][k + 3];
                a3 += v.x * w[3][k] + v.y * w[3][k + 1] + v.z * w[3][k + 2] + v.w * w[3][k + 3];
                a4 += v.x * w[4][k] + v.y * w[4][k + 1] + v.z * w[4][k + 2] + v.w * w[4][k + 3];
                a5 += v.x * w[5][k] + v.y * w[5][k + 1] + v.z * w[5][k + 2] + v.w * w[5][k + 3];
            }
            psL[psb]      = a0; psL[psb + 5]  = a1; psL[psb + 10] = a2;
            psL[psb + 15] = a3; psL[psb + 20] = a4; psL[psb + 25] = a5;
        }
        __syncthreads();   // ps ready; all x/h LDS reads of this iter done
        if (tid < HH) {
            if (s < TT) {
                const int j = tid;
                float acc[6];
#pragma unroll
                for (int gi = 0; gi < 6; ++gi) {
                    const int base = (gi * 128 + j) * 5;
                    acc[gi] = ps[base] + ps[base + 1] + ps[base + 2] + ps[base + 3];
                }
                const float rg = 1.f / (1.f + __expf(-(acc[0] + acc[3])));
                const float zg = 1.f / (1.f + __expf(-(acc[1] + acc[4])));
                const float narg = acc[2] + rg * acc[5];
                const float e2 = __expf(2.f * fabsf(narg));
                float ng = 1.f - 2.f / (e2 + 1.f);
                ng = (narg < 0.f) ? -ng : ng;
                const float hn = (1.f - zg) * ng + zg * hreg;
                h0s[j] = hn;
                x1[s & 1][j] = hn;        // layer-1 input for step s
                x0[j] = xnext;
                hreg = hn;
            }
        } else if (tid >= 512 && tid < 512 + HH) {
            if (s >= 1) {
                const int j = tid - 512;
                float acc[6];
#pragma unroll
                for (int gi = 0; gi < 6; ++gi) {
                    const int base = 3840 + (gi * 128 + j) * 5;
                    acc[gi] = ps[base] + ps[base + 1] + ps[base + 2] + ps[base + 3];
                }
                const float rg = 1.f / (1.f + __expf(-(acc[0] + acc[3])));
                const float zg = 1.f / (1.f + __expf(-(acc[1] + acc[4])));
                const float narg = acc[2] + rg * acc[5];
                const float e2 = __expf(2.f * fabsf(narg));
                float ng = 1.f - 2.f / (e2 + 1.f);
                ng = (narg < 0.f) ? -ng : ng;
                ob[(size_t)(s - 1) * HH + j] = __float2bfloat16(hreg);  // pre-update
                const float hn = (1.f - zg) * ng + zg * hreg;
                h1s[j] = hn;
                hreg = hn;
            }
        }
        __syncthreads();
    }
}

// ---------------------------------------------------------------------------
// head: all weights in registers; S7 done via 4-lane shuffle reduce (no LDS
// partials, no bank conflicts, no 64-deep serial reduce).
// ---------------------------------------------------------------------------
__device__ __forceinline__ void stage_xc(float* __restrict__ xc,
                                         const bf16* __restrict__ pu,
                                         const bf16* __restrict__ hl,
                                         int n0, int rb)
{
    const int T = threadIdx.x;
    const int base = n0 + rb * 8;
#pragma unroll
    for (int i = 0; i < 4; ++i) {
        const int idx = T + i * 512;
        const int r = idx >> 8, k = idx & 255;
        const size_t row = (size_t)(base + r);
        xc[r * 256 + k] = (k < 128) ? __bfloat162float(pu[row * HH + k])
                                    : __bfloat162float(hl[row * HH + (k - 128)]);
    }
}

__global__ __launch_bounds__(512, 2) void head_kernel(
    const bf16* __restrict__ pu, const bf16* __restrict__ hlast, const float* __restrict__ y_g,
    const float* __restrict__ dw1, const float* __restrict__ db1,
    const float* __restrict__ dw2, const float* __restrict__ db2,
    const float* __restrict__ xw, const float* __restrict__ xb,
    const float* __restrict__ pxw1, const float* __restrict__ pxb1,
    const float* __restrict__ pxw2, const float* __restrict__ pxb2,
    const float* __restrict__ mw1, const float* __restrict__ mb1,
    const float* __restrict__ mw2, const float* __restrict__ mb2,
    float* __restrict__ out, int s0, int nrows)
{
    __shared__ __align__(16) float ps[8192];
    __shared__ __align__(16) float xc[8 * 256];
    __shared__ __align__(16) float bP[8 * 128];
    __shared__ __align__(16) float bQ[8 * 128];
    __shared__ __align__(16) float bX[8 * 32];
    __shared__ __align__(16) float bias_l[688];
    __shared__ float red[8];
    const int T = threadIdx.x;

    if (T < 128) bias_l[T]       = db1[T];
    if (T < 128) bias_l[128 + T] = db2[T];
    if (T < 32)  bias_l[256 + T] = xb[T];
    if (T < 128) bias_l[288 + T] = pxb1[T];
    if (T < 128) bias_l[416 + T] = pxb2[T];
    if (T < 128) bias_l[544 + T] = mb1[T];
    if (T < 16)  bias_l[672 + T] = mb2[T];

    float w1[64]; loadw<128, 256, 8 >(w1, dw1);
    float w2[32]; loadw<128, 128, 8 >(w2, dw2);
    float w3[8];  loadw<32,  128, 32>(w3, xw);
    float w4[8];  loadw<128, 32,  8 >(w4, pxw1);
    float w5[32]; loadw<128, 128, 8 >(w5, pxw2);
    float w6[32]; loadw<128, 128, 8 >(w6, mw1);
    // S7: 4 lanes/output: lane = seg7*16 + j16 within wave r7
    const int j16 = T & 15, seg7 = (T >> 4) & 3, r7 = T >> 6;
    float w7[32];
#pragma unroll
    for (int kk = 0; kk < 32; kk += 4)
        *reinterpret_cast<float4*>(&w7[kk]) =
            *reinterpret_cast<const float4*>(&mw2[j16 * 128 + seg7 * 32 + kk]);

    float lossreg = 0.f;

    for (int tile = blockIdx.x; tile < nrows / 32; tile += gridDim.x) {
        const int n0 = tile * 32;
        const int b  = s0 + (n0 >> 11);
        const int t0 = n0 & (TT - 1);
        stage_xc(xc, pu, hlast, n0, 0);
#pragma unroll 1
        for (int rb = 0; rb < 4; ++rb) {
            __syncthreads();   // xc ready; ps free from previous batch
            rstage<128, 256, 8,  true >(w1, xc, 256, ps, bias_l + 0,   bP);
            rstage<128, 128, 8,  false>(w2, bP, 128, ps, bias_l + 128, bQ);
            rstage<32,  128, 32, false>(w3, bQ, 128, ps, bias_l + 256, bX);
            rstage<128, 32,  8,  true >(w4, bX, 32,  ps, bias_l + 288, bP);
            rstage<128, 128, 8,  false>(w5, bP, 128, ps, bias_l + 416, bQ);
            rstage<128, 128, 8,  true >(w6, bQ, 128, ps, bias_l + 544, bP);
            // S7 in registers: partial over 32 k, shuffle-reduce over 4 segs
            float p7 = 0.f;
#pragma unroll
            for (int kk = 0; kk < 32; kk += 4) {
                const float4 xv = *reinterpret_cast<const float4*>(&bP[r7 * 128 + seg7 * 32 + kk]);
                p7 += xv.x * w7[kk]     + xv.y * w7[kk + 1]
                    + xv.z * w7[kk + 2] + xv.w * w7[kk + 3];
            }
            p7 += __shfl_xor(p7, 16, 64);
            p7 += __shfl_xor(p7, 32, 64);
            if (seg7 == 0) {
                const int trow = t0 + rb * 8 + r7;
                const float yv = y_g[((size_t)b * YDIM + j16) * TT + trow];
                const float d = p7 + bias_l[672 + j16] - yv;
                lossreg += d * d;
            }
            if (rb < 3) stage_xc(xc, pu, hlast, n0, rb + 1);
        }
        __syncthreads();   // xc/bP reads done before next tile's writes
    }
#pragma unroll
    for (int off = 32; off > 0; off >>= 1) lossreg += __shfl_down(lossreg, off, 64);
    if ((T & 63) == 0) red[T >> 6] = lossreg;
    __syncthreads();
    if (T == 0) {
        float s = 0.f;
#pragma unroll
        for (int i = 0; i < 8; ++i) s += red[i];
        atomicAdd(out, s);
    }
}

__global__ void zero_out_kernel(float* o) { o[0] = 0.f; }

extern "C" void kernel_launch(void* const* d_in, const int* in_sizes, int n_in,
                              void* d_out, int out_size, void* d_ws, size_t ws_size,
                              hipStream_t stream)
{
    (void)in_sizes; (void)n_in; (void)out_size;
    const float* u    = (const float*)d_in[0];
    const float* y    = (const float*)d_in[1];
    const float* h0   = (const float*)d_in[2];
    const float* puw1 = (const float*)d_in[3];
    const float* pub1 = (const float*)d_in[4];
    const float* puw2 = (const float*)d_in[5];
    const float* pub2 = (const float*)d_in[6];
    const float* dw1  = (const float*)d_in[7];
    const float* db1  = (const float*)d_in[8];
    const float* dw2  = (const float*)d_in[9];
    const float* db2  = (const float*)d_in[10];
    const float* xw   = (const float*)d_in[11];
    const float* xbi  = (const float*)d_in[12];
    const float* pxw1 = (const float*)d_in[13];
    const float* pxb1 = (const float*)d_in[14];
    const float* pxw2 = (const float*)d_in[15];
    const float* pxb2 = (const float*)d_in[16];
    const float* mw1  = (const float*)d_in[17];
    const float* mb1  = (const float*)d_in[18];
    const float* mw2  = (const float*)d_in[19];
    const float* mb2  = (const float*)d_in[20];
    const float* gwih = (const float*)d_in[21];
    const float* gwhh = (const float*)d_in[22];

    const size_t per_sample = (size_t)TT * HH * 2 * 2;   // pu + hlast (bf16)
    int C = BB;
    while (C > 1 && (size_t)C * per_sample > ws_size) C >>= 1;
    bf16* puB = (bf16*)d_ws;
    bf16* hlB = puB + (size_t)C * TT * HH;

    zero_out_kernel<<<1, 1, 0, stream>>>((float*)d_out);
    for (int s0 = 0; s0 < BB; s0 += C) {
        phi_u_kernel<<<512, 512, 0, stream>>>(u, puw1, pub1, puw2, pub2, puB, s0, C * TT);
        gru_fused_kernel<<<C, 1024, 0, stream>>>(puB, gwih, gwhh, h0, hlB, s0);
        head_kernel<<<512, 512, 0, stream>>>(puB, hlB, y,
                                             dw1, db1, dw2, db2, xw, xbi,
                                             pxw1, pxb1, pxw2, pxb2,
                                             mw1, mb1, mw2, mb2,
                                             (float*)d_out, s0, C * TT);
    }
}

// Round 8
// 8142.130 us; speedup vs baseline: 4.2843x; 4.2843x over previous
//
#include <hip/hip_runtime.h>
#include <hip/hip_bf16.h>

#define TT 2048
#define BB 256
#define HH 128
#define UDIM 16
#define YDIM 16
#define ZDIM 32
#define H3 384

typedef __hip_bfloat16 bf16;

constexpr int clog2(int x) { return x <= 1 ? 0 : 1 + clog2(x >> 1); }

// ---------------------------------------------------------------------------
// Register-weight linear stage (phi_u + head). Mapping (M,K,O; O*(M/2)=512,
// F=K/O): thread T owns rows jb=T&(M/2-1), jb+M/2, col-chunk o=T>>log2(M/2).
// ---------------------------------------------------------------------------
template <int M_, int K_, int O_, bool RELU_>
__device__ __forceinline__ void rstage(const float* __restrict__ wfrag,
                                       const float* __restrict__ xin, int XS,
                                       float* __restrict__ ps,
                                       const float* __restrict__ bias,
                                       float* __restrict__ outb)
{
    constexpr int F = K_ / O_;
    const int T = threadIdx.x;
    const int jb = T & (M_ / 2 - 1);
    const int o  = T >> clog2(M_ / 2);
#pragma unroll
    for (int r = 0; r < 8; ++r) {
        float a0 = 0.f, a1 = 0.f;
#pragma unroll
        for (int g = 0; g < F; g += 4) {
            const float4 xv = *reinterpret_cast<const float4*>(&xin[r * XS + o * F + g]);
            a0 += xv.x * wfrag[g]     + xv.y * wfrag[g + 1]
                + xv.z * wfrag[g + 2] + xv.w * wfrag[g + 3];
            a1 += xv.x * wfrag[F + g]     + xv.y * wfrag[F + g + 1]
                + xv.z * wfrag[F + g + 2] + xv.w * wfrag[F + g + 3];
        }
        ps[r * 1024 + o * M_ + jb]           = a0;
        ps[r * 1024 + o * M_ + jb + M_ / 2]  = a1;
    }
    __syncthreads();
    for (int oi = T; oi < 8 * M_; oi += 512) {
        const int r = oi >> clog2(M_);
        const int j = oi & (M_ - 1);
        float s = bias[j];
#pragma unroll
        for (int o2 = 0; o2 < O_; ++o2) s += ps[r * 1024 + o2 * M_ + j];
        if (RELU_) s = fmaxf(s, 0.f);
        outb[r * M_ + j] = s;
    }
    __syncthreads();
}

template <int M_, int K_, int O_>
__device__ __forceinline__ void loadw(float* __restrict__ wfrag, const float* __restrict__ Wg)
{
    constexpr int F = K_ / O_;
    const int T = threadIdx.x;
    const int jb = T & (M_ / 2 - 1);
    const int o  = T >> clog2(M_ / 2);
#pragma unroll
    for (int h = 0; h < 2; ++h)
#pragma unroll
        for (int g = 0; g < F; g += 4)
            *reinterpret_cast<float4*>(&wfrag[h * F + g]) =
                *reinterpret_cast<const float4*>(&Wg[(jb + h * (M_ / 2)) * K_ + o * F + g]);
}

// ---------------------------------------------------------------------------
// phi_u: register weights, persistent 512 blocks.
// ---------------------------------------------------------------------------
__global__ __launch_bounds__(512, 2) void phi_u_kernel(
    const float* __restrict__ u, const float* __restrict__ w1, const float* __restrict__ b1,
    const float* __restrict__ w2, const float* __restrict__ b2,
    bf16* __restrict__ pu, int s0, int nrows)
{
    __shared__ __align__(16) float ps[8192];
    __shared__ __align__(16) float xc[8 * 16];
    __shared__ __align__(16) float bP[8 * 128];
    __shared__ __align__(16) float bias_l[256];
    const int T = threadIdx.x;
    if (T < 128) { bias_l[T] = b1[T]; bias_l[128 + T] = b2[T]; }
    const int jb = T & 63, o = T >> 6;
    float wa[4];
    wa[0] = w1[jb * 16 + o * 2];        wa[1] = w1[jb * 16 + o * 2 + 1];
    wa[2] = w1[(jb + 64) * 16 + o * 2]; wa[3] = w1[(jb + 64) * 16 + o * 2 + 1];
    float wb[32]; loadw<128, 128, 8>(wb, w2);
    __syncthreads();

    for (int tile = blockIdx.x; tile < nrows / 32; tile += gridDim.x) {
        const int n0 = tile * 32;
        const int b  = s0 + (n0 >> 11);
        const int t0 = n0 & (TT - 1);
#pragma unroll 1
        for (int rb = 0; rb < 4; ++rb) {
            if (T < 128) {
                const int r = T & 7, c = T >> 3;
                xc[r * 16 + c] = u[((size_t)b * UDIM + c) * TT + t0 + rb * 8 + r];
            }
            __syncthreads();
#pragma unroll
            for (int r = 0; r < 8; ++r) {
                const float x0 = xc[r * 16 + o * 2], x1 = xc[r * 16 + o * 2 + 1];
                ps[r * 1024 + o * 128 + jb]      = x0 * wa[0] + x1 * wa[1];
                ps[r * 1024 + o * 128 + jb + 64] = x0 * wa[2] + x1 * wa[3];
            }
            __syncthreads();
            for (int oi = T; oi < 8 * 128; oi += 512) {
                const int r = oi >> 7, j = oi & 127;
                float s = bias_l[j];
#pragma unroll
                for (int o2 = 0; o2 < 8; ++o2) s += ps[r * 1024 + o2 * 128 + j];
                bP[r * 128 + j] = fmaxf(s, 0.f);
            }
            __syncthreads();
            rstage<128, 128, 8, false>(wb, bP, 128, ps, bias_l + 128, bP);
            const int row0 = n0 + rb * 8;
            for (int oi = T; oi < 8 * 128; oi += 512) {
                const int r = oi >> 7, j = oi & 127;
                pu[(size_t)(row0 + r) * HH + j] = __float2bfloat16(bP[r * 128 + j]);
            }
            __syncthreads();
        }
    }
}

// ---------------------------------------------------------------------------
// Sequential GRU pass, one layer, one block/sample, 512 threads (8 waves).
// Task map: wave g=t>>6 -> matrix m=g>>2 (0:wih,1:whh), slice o=g&3;
// lane u=t&63 owns rows u+64i (i=0..5) of matrix m, cols [o*32, o*32+32).
// One 32-float vector slice (8 broadcast ds_read_b128) feeds 192 FMAs.
// Partials ps[o*768 + m*384 + row]: lane-stride-1 writes AND reads ->
// zero bank conflicts. Threads 0..127 assemble gates (stride-768 scalar
// reads, lanes consecutive -> conflict-free).
// 192 weight floats/thread -> VGPR+AGPR resident (8 waves fit the unified
// file; do NOT raise block size - 16 waves would spill to scratch, round 7).
// store_prev=1 emits the state ENTERING step t. h_out may alias x_in
// (same thread reads x[t+1] before writing out[t]).
// ---------------------------------------------------------------------------
__global__ __launch_bounds__(512, 2) void gru_pass_kernel(
    const bf16* __restrict__ x_in, const float* __restrict__ wih,
    const float* __restrict__ whh, const float* __restrict__ h0_l,
    bf16* __restrict__ h_out, int store_prev, int s0)
{
    const int t = threadIdx.x;
    __shared__ __align__(16) float x_lds[HH];
    __shared__ __align__(16) float h_lds[HH];
    __shared__ __align__(16) float ps[3072];   // [o][m][row]

    const int g = t >> 6;        // wave-uniform
    const int m = g >> 2, o = g & 3;
    const int u = t & 63;
    const float* Wmat = (m == 0) ? wih : whh;
    float w[6][32];
#pragma unroll
    for (int i = 0; i < 6; ++i)
#pragma unroll
        for (int k = 0; k < 32; k += 4)
            *reinterpret_cast<float4*>(&w[i][k]) =
                *reinterpret_cast<const float4*>(&Wmat[(u + 64 * i) * HH + o * 32 + k]);
    const float* vec = ((m == 0) ? x_lds : h_lds) + o * 32;
    const int psb = o * 768 + m * 384 + u;

    const bf16* xb = x_in + (size_t)blockIdx.x * TT * HH;
    bf16* ob = h_out + (size_t)blockIdx.x * TT * HH;
    float hreg = 0.f;
    if (t < HH) {
        hreg = h0_l[(size_t)(s0 + blockIdx.x) * HH + t];
        h_lds[t] = hreg;
        x_lds[t] = __bfloat162float(xb[t]);
    }
    __syncthreads();

#pragma unroll 1
    for (int step = 0; step < TT; ++step) {
        float xnext = 0.f;
        if (t < HH && step + 1 < TT)
            xnext = __bfloat162float(xb[(size_t)(step + 1) * HH + t]);  // prefetch
        float a0 = 0.f, a1 = 0.f, a2 = 0.f, a3 = 0.f, a4 = 0.f, a5 = 0.f;
#pragma unroll
        for (int k = 0; k < 32; k += 4) {
            const float4 v = *reinterpret_cast<const float4*>(&vec[k]);
            a0 += v.x * w[0][k] + v.y * w[0][k + 1] + v.z * w[0][k + 2] + v.w * w[0][k + 3];
            a1 += v.x * w[1][k] + v.y * w[1][k + 1] + v.z * w[1][k + 2] + v.w * w[1][k + 3];
            a2 += v.x * w[2][k] + v.y * w[2][k + 1] + v.z * w[2][k + 2] + v.w * w[2][k + 3];
            a3 += v.x * w[3][k] + v.y * w[3][k + 1] + v.z * w[3][k + 2] + v.w * w[3][k + 3];
            a4 += v.x * w[4][k] + v.y * w[4][k + 1] + v.z * w[4][k + 2] + v.w * w[4][k + 3];
            a5 += v.x * w[5][k] + v.y * w[5][k + 1] + v.z * w[5][k + 2] + v.w * w[5][k + 3];
        }
        ps[psb]       = a0; ps[psb + 64]  = a1; ps[psb + 128] = a2;
        ps[psb + 192] = a3; ps[psb + 256] = a4; ps[psb + 320] = a5;
        __syncthreads();   // ps ready; all x/h LDS reads done
        if (t < HH) {
            const int j = t;
            float gir = 0.f, giz = 0.f, gin = 0.f, ghr = 0.f, ghz = 0.f, ghn = 0.f;
#pragma unroll
            for (int o2 = 0; o2 < 4; ++o2) {
                const int base = o2 * 768;
                gir += ps[base + j];
                giz += ps[base + 128 + j];
                gin += ps[base + 256 + j];
                ghr += ps[base + 384 + j];
                ghz += ps[base + 512 + j];
                ghn += ps[base + 640 + j];
            }
            const float rg = 1.f / (1.f + __expf(-(gir + ghr)));
            const float zg = 1.f / (1.f + __expf(-(giz + ghz)));
            const float narg = gin + rg * ghn;
            const float e2 = __expf(2.f * fabsf(narg));
            float ng = 1.f - 2.f / (e2 + 1.f);          // |tanh|, inf-safe
            ng = (narg < 0.f) ? -ng : ng;
            const float hn = (1.f - zg) * ng + zg * hreg;
            ob[(size_t)step * HH + t] = __float2bfloat16(store_prev ? hreg : hn);
            h_lds[t] = hn;
            x_lds[t] = xnext;
            hreg = hn;
        }
        __syncthreads();   // h/x updated for next step
    }
}

// ---------------------------------------------------------------------------
// head: all weights in registers; S7 via 4-lane shuffle reduce.
// ---------------------------------------------------------------------------
__device__ __forceinline__ void stage_xc(float* __restrict__ xc,
                                         const bf16* __restrict__ pu,
                                         const bf16* __restrict__ hl,
                                         int n0, int rb)
{
    const int T = threadIdx.x;
    const int base = n0 + rb * 8;
#pragma unroll
    for (int i = 0; i < 4; ++i) {
        const int idx = T + i * 512;
        const int r = idx >> 8, k = idx & 255;
        const size_t row = (size_t)(base + r);
        xc[r * 256 + k] = (k < 128) ? __bfloat162float(pu[row * HH + k])
                                    : __bfloat162float(hl[row * HH + (k - 128)]);
    }
}

__global__ __launch_bounds__(512, 2) void head_kernel(
    const bf16* __restrict__ pu, const bf16* __restrict__ hlast, const float* __restrict__ y_g,
    const float* __restrict__ dw1, const float* __restrict__ db1,
    const float* __restrict__ dw2, const float* __restrict__ db2,
    const float* __restrict__ xw, const float* __restrict__ xb,
    const float* __restrict__ pxw1, const float* __restrict__ pxb1,
    const float* __restrict__ pxw2, const float* __restrict__ pxb2,
    const float* __restrict__ mw1, const float* __restrict__ mb1,
    const float* __restrict__ mw2, const float* __restrict__ mb2,
    float* __restrict__ out, int s0, int nrows)
{
    __shared__ __align__(16) float ps[8192];
    __shared__ __align__(16) float xc[8 * 256];
    __shared__ __align__(16) float bP[8 * 128];
    __shared__ __align__(16) float bQ[8 * 128];
    __shared__ __align__(16) float bX[8 * 32];
    __shared__ __align__(16) float bias_l[688];
    __shared__ float red[8];
    const int T = threadIdx.x;

    if (T < 128) bias_l[T]       = db1[T];
    if (T < 128) bias_l[128 + T] = db2[T];
    if (T < 32)  bias_l[256 + T] = xb[T];
    if (T < 128) bias_l[288 + T] = pxb1[T];
    if (T < 128) bias_l[416 + T] = pxb2[T];
    if (T < 128) bias_l[544 + T] = mb1[T];
    if (T < 16)  bias_l[672 + T] = mb2[T];

    float w1[64]; loadw<128, 256, 8 >(w1, dw1);
    float w2[32]; loadw<128, 128, 8 >(w2, dw2);
    float w3[8];  loadw<32,  128, 32>(w3, xw);
    float w4[8];  loadw<128, 32,  8 >(w4, pxw1);
    float w5[32]; loadw<128, 128, 8 >(w5, pxw2);
    float w6[32]; loadw<128, 128, 8 >(w6, mw1);
    const int j16 = T & 15, seg7 = (T >> 4) & 3, r7 = T >> 6;
    float w7[32];
#pragma unroll
    for (int kk = 0; kk < 32; kk += 4)
        *reinterpret_cast<float4*>(&w7[kk]) =
            *reinterpret_cast<const float4*>(&mw2[j16 * 128 + seg7 * 32 + kk]);

    float lossreg = 0.f;

    for (int tile = blockIdx.x; tile < nrows / 32; tile += gridDim.x) {
        const int n0 = tile * 32;
        const int b  = s0 + (n0 >> 11);
        const int t0 = n0 & (TT - 1);
        stage_xc(xc, pu, hlast, n0, 0);
#pragma unroll 1
        for (int rb = 0; rb < 4; ++rb) {
            __syncthreads();   // xc ready; ps free from previous batch
            rstage<128, 256, 8,  true >(w1, xc, 256, ps, bias_l + 0,   bP);
            rstage<128, 128, 8,  false>(w2, bP, 128, ps, bias_l + 128, bQ);
            rstage<32,  128, 32, false>(w3, bQ, 128, ps, bias_l + 256, bX);
            rstage<128, 32,  8,  true >(w4, bX, 32,  ps, bias_l + 288, bP);
            rstage<128, 128, 8,  false>(w5, bP, 128, ps, bias_l + 416, bQ);
            rstage<128, 128, 8,  true >(w6, bQ, 128, ps, bias_l + 544, bP);
            // S7 in registers: partial over 32 k, shuffle-reduce over 4 segs
            float p7 = 0.f;
#pragma unroll
            for (int kk = 0; kk < 32; kk += 4) {
                const float4 xv = *reinterpret_cast<const float4*>(&bP[r7 * 128 + seg7 * 32 + kk]);
                p7 += xv.x * w7[kk]     + xv.y * w7[kk + 1]
                    + xv.z * w7[kk + 2] + xv.w * w7[kk + 3];
            }
            p7 += __shfl_xor(p7, 16, 64);
            p7 += __shfl_xor(p7, 32, 64);
            if (seg7 == 0) {
                const int trow = t0 + rb * 8 + r7;
                const float yv = y_g[((size_t)b * YDIM + j16) * TT + trow];
                const float d = p7 + bias_l[672 + j16] - yv;
                lossreg += d * d;
            }
            if (rb < 3) stage_xc(xc, pu, hlast, n0, rb + 1);
        }
        __syncthreads();   // xc/bP reads done before next tile's writes
    }
#pragma unroll
    for (int off = 32; off > 0; off >>= 1) lossreg += __shfl_down(lossreg, off, 64);
    if ((T & 63) == 0) red[T >> 6] = lossreg;
    __syncthreads();
    if (T == 0) {
        float s = 0.f;
#pragma unroll
        for (int i = 0; i < 8; ++i) s += red[i];
        atomicAdd(out, s);
    }
}

__global__ void zero_out_kernel(float* o) { o[0] = 0.f; }

extern "C" void kernel_launch(void* const* d_in, const int* in_sizes, int n_in,
                              void* d_out, int out_size, void* d_ws, size_t ws_size,
                              hipStream_t stream)
{
    (void)in_sizes; (void)n_in; (void)out_size;
    const float* u    = (const float*)d_in[0];
    const float* y    = (const float*)d_in[1];
    const float* h0   = (const float*)d_in[2];
    const float* puw1 = (const float*)d_in[3];
    const float* pub1 = (const float*)d_in[4];
    const float* puw2 = (const float*)d_in[5];
    const float* pub2 = (const float*)d_in[6];
    const float* dw1  = (const float*)d_in[7];
    const float* db1  = (const float*)d_in[8];
    const float* dw2  = (const float*)d_in[9];
    const float* db2  = (const float*)d_in[10];
    const float* xw   = (const float*)d_in[11];
    const float* xbi  = (const float*)d_in[12];
    const float* pxw1 = (const float*)d_in[13];
    const float* pxb1 = (const float*)d_in[14];
    const float* pxw2 = (const float*)d_in[15];
    const float* pxb2 = (const float*)d_in[16];
    const float* mw1  = (const float*)d_in[17];
    const float* mb1  = (const float*)d_in[18];
    const float* mw2  = (const float*)d_in[19];
    const float* mb2  = (const float*)d_in[20];
    const float* gwih = (const float*)d_in[21];
    const float* gwhh = (const float*)d_in[22];

    const size_t per_sample = (size_t)TT * HH * 2 * 2;   // pu + traj (bf16)
    int C = BB;
    while (C > 1 && (size_t)C * per_sample > ws_size) C >>= 1;
    bf16* puB = (bf16*)d_ws;
    bf16* trB = puB + (size_t)C * TT * HH;   // pass-B out aliases its in (safe)

    zero_out_kernel<<<1, 1, 0, stream>>>((float*)d_out);
    for (int s0 = 0; s0 < BB; s0 += C) {
        phi_u_kernel<<<512, 512, 0, stream>>>(u, puw1, pub1, puw2, pub2, puB, s0, C * TT);
        gru_pass_kernel<<<C, 512, 0, stream>>>(puB, gwih, gwhh, h0, trB, 0, s0);
        gru_pass_kernel<<<C, 512, 0, stream>>>(trB, gwih + H3 * HH, gwhh + H3 * HH,
                                               h0 + BB * HH, trB, 1, s0);
        head_kernel<<<512, 512, 0, stream>>>(puB, trB, y,
                                             dw1, db1, dw2, db2, xw, xbi,
                                             pxw1, pxb1, pxw2, pxb2,
                                             mw1, mb1, mw2, mb2,
                                             (float*)d_out, s0, C * TT);
    }
}

// Round 10
// 8118.215 us; speedup vs baseline: 4.2970x; 1.0029x over previous
//
#include <hip/hip_runtime.h>
#include <hip/hip_bf16.h>

#define TT 2048
#define BB 256
#define HH 128
#define UDIM 16
#define YDIM 16
#define ZDIM 32
#define H3 384

typedef __hip_bfloat16 bf16;
typedef _Float16 half2v __attribute__((ext_vector_type(2)));

constexpr int clog2(int x) { return x <= 1 ? 0 : 1 + clog2(x >> 1); }

// ---------------------------------------------------------------------------
// Register-weight linear stage (phi_u + head). Mapping (M,K,O; O*(M/2)=512,
// F=K/O): thread T owns rows jb=T&(M/2-1), jb+M/2, col-chunk o=T>>log2(M/2).
// ---------------------------------------------------------------------------
template <int M_, int K_, int O_, bool RELU_>
__device__ __forceinline__ void rstage(const float* __restrict__ wfrag,
                                       const float* __restrict__ xin, int XS,
                                       float* __restrict__ ps,
                                       const float* __restrict__ bias,
                                       float* __restrict__ outb)
{
    constexpr int F = K_ / O_;
    const int T = threadIdx.x;
    const int jb = T & (M_ / 2 - 1);
    const int o  = T >> clog2(M_ / 2);
#pragma unroll
    for (int r = 0; r < 8; ++r) {
        float a0 = 0.f, a1 = 0.f;
#pragma unroll
        for (int g = 0; g < F; g += 4) {
            const float4 xv = *reinterpret_cast<const float4*>(&xin[r * XS + o * F + g]);
            a0 += xv.x * wfrag[g]     + xv.y * wfrag[g + 1]
                + xv.z * wfrag[g + 2] + xv.w * wfrag[g + 3];
            a1 += xv.x * wfrag[F + g]     + xv.y * wfrag[F + g + 1]
                + xv.z * wfrag[F + g + 2] + xv.w * wfrag[F + g + 3];
        }
        ps[r * 1024 + o * M_ + jb]           = a0;
        ps[r * 1024 + o * M_ + jb + M_ / 2]  = a1;
    }
    __syncthreads();
    for (int oi = T; oi < 8 * M_; oi += 512) {
        const int r = oi >> clog2(M_);
        const int j = oi & (M_ - 1);
        float s = bias[j];
#pragma unroll
        for (int o2 = 0; o2 < O_; ++o2) s += ps[r * 1024 + o2 * M_ + j];
        if (RELU_) s = fmaxf(s, 0.f);
        outb[r * M_ + j] = s;
    }
    __syncthreads();
}

template <int M_, int K_, int O_>
__device__ __forceinline__ void loadw(float* __restrict__ wfrag, const float* __restrict__ Wg)
{
    constexpr int F = K_ / O_;
    const int T = threadIdx.x;
    const int jb = T & (M_ / 2 - 1);
    const int o  = T >> clog2(M_ / 2);
#pragma unroll
    for (int h = 0; h < 2; ++h)
#pragma unroll
        for (int g = 0; g < F; g += 4)
            *reinterpret_cast<float4*>(&wfrag[h * F + g]) =
                *reinterpret_cast<const float4*>(&Wg[(jb + h * (M_ / 2)) * K_ + o * F + g]);
}

// ---------------------------------------------------------------------------
// phi_u: register weights, persistent 512 blocks (unchanged).
// ---------------------------------------------------------------------------
__global__ __launch_bounds__(512, 2) void phi_u_kernel(
    const float* __restrict__ u, const float* __restrict__ w1, const float* __restrict__ b1,
    const float* __restrict__ w2, const float* __restrict__ b2,
    bf16* __restrict__ pu, int s0, int nrows)
{
    __shared__ __align__(16) float ps[8192];
    __shared__ __align__(16) float xc[8 * 16];
    __shared__ __align__(16) float bP[8 * 128];
    __shared__ __align__(16) float bias_l[256];
    const int T = threadIdx.x;
    if (T < 128) { bias_l[T] = b1[T]; bias_l[128 + T] = b2[T]; }
    const int jb = T & 63, o = T >> 6;
    float wa[4];
    wa[0] = w1[jb * 16 + o * 2];        wa[1] = w1[jb * 16 + o * 2 + 1];
    wa[2] = w1[(jb + 64) * 16 + o * 2]; wa[3] = w1[(jb + 64) * 16 + o * 2 + 1];
    float wb[32]; loadw<128, 128, 8>(wb, w2);
    __syncthreads();

    for (int tile = blockIdx.x; tile < nrows / 32; tile += gridDim.x) {
        const int n0 = tile * 32;
        const int b  = s0 + (n0 >> 11);
        const int t0 = n0 & (TT - 1);
#pragma unroll 1
        for (int rb = 0; rb < 4; ++rb) {
            if (T < 128) {
                const int r = T & 7, c = T >> 3;
                xc[r * 16 + c] = u[((size_t)b * UDIM + c) * TT + t0 + rb * 8 + r];
            }
            __syncthreads();
#pragma unroll
            for (int r = 0; r < 8; ++r) {
                const float x0 = xc[r * 16 + o * 2], x1 = xc[r * 16 + o * 2 + 1];
                ps[r * 1024 + o * 128 + jb]      = x0 * wa[0] + x1 * wa[1];
                ps[r * 1024 + o * 128 + jb + 64] = x0 * wa[2] + x1 * wa[3];
            }
            __syncthreads();
            for (int oi = T; oi < 8 * 128; oi += 512) {
                const int r = oi >> 7, j = oi & 127;
                float s = bias_l[j];
#pragma unroll
                for (int o2 = 0; o2 < 8; ++o2) s += ps[r * 1024 + o2 * 128 + j];
                bP[r * 128 + j] = fmaxf(s, 0.f);
            }
            __syncthreads();
            rstage<128, 128, 8, false>(wb, bP, 128, ps, bias_l + 128, bP);
            const int row0 = n0 + rb * 8;
            for (int oi = T; oi < 8 * 128; oi += 512) {
                const int r = oi >> 7, j = oi & 127;
                pu[(size_t)(row0 + r) * HH + j] = __float2bfloat16(bP[r * 128 + j]);
            }
            __syncthreads();
        }
    }
}

// ---------------------------------------------------------------------------
// GRU pass v3: f16 weights + v_dot2_f32_f16, role-split gate tail.
// 512 threads; wave g -> matrix m=g>>2, slice o=g&3; lane u owns rows u+64i
// (i=0..5): 96 half2 weight VGPRs, 96 fdot2 per step, 4 broadcast b128 reads.
// Partials ps[o*768+m*384+row] (lane-stride-1, conflict-free).
// Gate tail on threads 0..255: j=t>>1, role=t&1. role0: r,z sums (16 reads)
// + sigmoids + x_{t+1} prefetch; role1: n sums (8 reads) + tanh + h update
// (state fp32 in role1 registers). r,z cross via converged __shfl_xor(1);
// h/x packed to half2 LDS via converged __shfl_down(2).
// store_prev=1 emits the state ENTERING step t. h_out may alias x_in.
// ---------------------------------------------------------------------------
__global__ __launch_bounds__(512, 2) void gru_pass_kernel(
    const bf16* __restrict__ x_in, const float* __restrict__ wih,
    const float* __restrict__ whh, const float* __restrict__ h0_l,
    bf16* __restrict__ h_out, int store_prev, int s0)
{
    const int t = threadIdx.x;
    __shared__ __align__(16) half2v x2[64];
    __shared__ __align__(16) half2v hh2[64];
    __shared__ __align__(16) float ps[3072];

    const int g = t >> 6;        // wave-uniform
    const int m = g >> 2, o = g & 3;
    const int u = t & 63;
    const float* Wmat = (m == 0) ? wih : whh;
    half2v w[6][16];
#pragma unroll
    for (int i = 0; i < 6; ++i) {
        const float* src = &Wmat[(u + 64 * i) * HH + o * 32];
#pragma unroll
        for (int k = 0; k < 16; ++k) {
            half2v v; v.x = (_Float16)src[2 * k]; v.y = (_Float16)src[2 * k + 1];
            w[i][k] = v;
        }
    }
    const half2v* vec2 = ((m == 0) ? x2 : hh2) + o * 16;
    const int psb = o * 768 + m * 384 + u;

    const bf16* xb = x_in + (size_t)blockIdx.x * TT * HH;
    bf16* ob = h_out + (size_t)blockIdx.x * TT * HH;

    float hreg = 0.f;            // role1 threads hold h state (fp32)
    if (t < 256) {
        const int j = t >> 1;
        float pv;
        if (t & 1) { hreg = h0_l[(size_t)(s0 + blockIdx.x) * HH + j]; pv = hreg; }
        else       { pv = __bfloat162float(xb[j]); }
        const float pw = __shfl_down(pv, 2, 64);
        if ((t & 3) == 1) { half2v v; v.x = (_Float16)pv; v.y = (_Float16)pw; hh2[t >> 2] = v; }
        else if ((t & 3) == 0) { half2v v; v.x = (_Float16)pv; v.y = (_Float16)pw; x2[t >> 2] = v; }
    }
    __syncthreads();

#pragma unroll 1
    for (int step = 0; step < TT; ++step) {
        float a0 = 0.f, a1 = 0.f, a2 = 0.f, a3 = 0.f, a4 = 0.f, a5 = 0.f;
#pragma unroll
        for (int k4 = 0; k4 < 4; ++k4) {
            half2v xt[4];
            *reinterpret_cast<float4*>(xt) = reinterpret_cast<const float4*>(vec2)[k4];
#pragma unroll
            for (int e = 0; e < 4; ++e) {
                const int k = k4 * 4 + e;
                a0 = __builtin_amdgcn_fdot2(xt[e], w[0][k], a0, false);
                a1 = __builtin_amdgcn_fdot2(xt[e], w[1][k], a1, false);
                a2 = __builtin_amdgcn_fdot2(xt[e], w[2][k], a2, false);
                a3 = __builtin_amdgcn_fdot2(xt[e], w[3][k], a3, false);
                a4 = __builtin_amdgcn_fdot2(xt[e], w[4][k], a4, false);
                a5 = __builtin_amdgcn_fdot2(xt[e], w[5][k], a5, false);
            }
        }
        ps[psb]       = a0; ps[psb + 64]  = a1; ps[psb + 128] = a2;
        ps[psb + 192] = a3; ps[psb + 256] = a4; ps[psb + 320] = a5;
        __syncthreads();   // ps ready; all x2/hh2 reads done
        if (t < 256) {
            const int j = t >> 1;
            float v0, v1, xnext = 0.f;
            if (t & 1) {   // role1: n-gate sums
                float gin = 0.f, ghn = 0.f;
#pragma unroll
                for (int o2 = 0; o2 < 4; ++o2) {
                    gin += ps[o2 * 768 + 256 + j];
                    ghn += ps[o2 * 768 + 640 + j];
                }
                v0 = gin; v1 = ghn;
            } else {       // role0: r,z sums + sigmoids + x prefetch
                float gr = 0.f, gz = 0.f;
#pragma unroll
                for (int o2 = 0; o2 < 4; ++o2) {
                    gr += ps[o2 * 768 + j]       + ps[o2 * 768 + 384 + j];
                    gz += ps[o2 * 768 + 128 + j] + ps[o2 * 768 + 512 + j];
                }
                v0 = 1.f / (1.f + __expf(-gr));
                v1 = 1.f / (1.f + __expf(-gz));
                if (step + 1 < TT) xnext = __bfloat162float(xb[(size_t)(step + 1) * HH + j]);
            }
            const float rS = __shfl_xor(v0, 1, 64);   // role1 receives r
            const float zS = __shfl_xor(v1, 1, 64);   // role1 receives z
            if (t & 1) {
                const float narg = v0 + rS * v1;
                const float e2 = __expf(2.f * fabsf(narg));
                float ng = 1.f - 2.f / (e2 + 1.f);    // |tanh|, inf-safe
                ng = (narg < 0.f) ? -ng : ng;
                const float hn = (1.f - zS) * ng + zS * hreg;
                ob[(size_t)step * HH + j] = __float2bfloat16(store_prev ? hreg : hn);
                hreg = hn;
            }
            const float pv = (t & 1) ? hreg : xnext;
            const float pw = __shfl_down(pv, 2, 64);
            if ((t & 3) == 1) { half2v v; v.x = (_Float16)pv; v.y = (_Float16)pw; hh2[t >> 2] = v; }
            else if ((t & 3) == 0) { half2v v; v.x = (_Float16)pv; v.y = (_Float16)pw; x2[t >> 2] = v; }
        }
        __syncthreads();   // h/x updated for next step
    }
}

// ---------------------------------------------------------------------------
// head: round-6 version (known 2.56 ms) — all weights in registers, S7 via
// LDS partials + 128-thread reduce. (Round-8 shuffle S7 was slower: 4-way
// conflicted bP reads + ds-permute cost.)
// ---------------------------------------------------------------------------
__device__ __forceinline__ void stage_xc(float* __restrict__ xc,
                                         const bf16* __restrict__ pu,
                                         const bf16* __restrict__ hl,
                                         int n0, int rb)
{
    const int T = threadIdx.x;
    const int base = n0 + rb * 8;
#pragma unroll
    for (int i = 0; i < 4; ++i) {
        const int idx = T + i * 512;
        const int r = idx >> 8, k = idx & 255;
        const size_t row = (size_t)(base + r);
        xc[r * 256 + k] = (k < 128) ? __bfloat162float(pu[row * HH + k])
                                    : __bfloat162float(hl[row * HH + (k - 128)]);
    }
}

__global__ __launch_bounds__(512, 2) void head_kernel(
    const bf16* __restrict__ pu, const bf16* __restrict__ hlast, const float* __restrict__ y_g,
    const float* __restrict__ dw1, const float* __restrict__ db1,
    const float* __restrict__ dw2, const float* __restrict__ db2,
    const float* __restrict__ xw, const float* __restrict__ xb,
    const float* __restrict__ pxw1, const float* __restrict__ pxb1,
    const float* __restrict__ pxw2, const float* __restrict__ pxb2,
    const float* __restrict__ mw1, const float* __restrict__ mb1,
    const float* __restrict__ mw2, const float* __restrict__ mb2,
    float* __restrict__ out, int s0, int nrows)
{
    __shared__ __align__(16) float ps[8192];
    __shared__ __align__(16) float xc[8 * 256];
    __shared__ __align__(16) float bP[8 * 128];
    __shared__ __align__(16) float bQ[8 * 128];
    __shared__ __align__(16) float bX[8 * 32];
    __shared__ __align__(16) float bias_l[688];
    __shared__ float red[8];
    const int T = threadIdx.x;

    if (T < 128) bias_l[T]       = db1[T];
    if (T < 128) bias_l[128 + T] = db2[T];
    if (T < 32)  bias_l[256 + T] = xb[T];
    if (T < 128) bias_l[288 + T] = pxb1[T];
    if (T < 128) bias_l[416 + T] = pxb2[T];
    if (T < 128) bias_l[544 + T] = mb1[T];
    if (T < 16)  bias_l[672 + T] = mb2[T];

    float w1[64]; loadw<128, 256, 8 >(w1, dw1);
    float w2[32]; loadw<128, 128, 8 >(w2, dw2);
    float w3[8];  loadw<32,  128, 32>(w3, xw);
    float w4[8];  loadw<128, 32,  8 >(w4, pxw1);
    float w5[32]; loadw<128, 128, 8 >(w5, pxw2);
    float w6[32]; loadw<128, 128, 8 >(w6, mw1);
    const int jb7 = T & 7, o7 = T >> 3;   // S7: M=16,K=128,O=64,F=2
    float w7[4];
    w7[0] = mw2[jb7 * 128 + 2 * o7];       w7[1] = mw2[jb7 * 128 + 2 * o7 + 1];
    w7[2] = mw2[(jb7 + 8) * 128 + 2 * o7]; w7[3] = mw2[(jb7 + 8) * 128 + 2 * o7 + 1];

    float lossreg = 0.f;

    for (int tile = blockIdx.x; tile < nrows / 32; tile += gridDim.x) {
        const int n0 = tile * 32;
        const int b  = s0 + (n0 >> 11);
        const int t0 = n0 & (TT - 1);
        stage_xc(xc, pu, hlast, n0, 0);
#pragma unroll 1
        for (int rb = 0; rb < 4; ++rb) {
            __syncthreads();   // xc ready; ps free from previous batch
            rstage<128, 256, 8,  true >(w1, xc, 256, ps, bias_l + 0,   bP);
            rstage<128, 128, 8,  false>(w2, bP, 128, ps, bias_l + 128, bQ);
            rstage<32,  128, 32, false>(w3, bQ, 128, ps, bias_l + 256, bX);
            rstage<128, 32,  8,  true >(w4, bX, 32,  ps, bias_l + 288, bP);
            rstage<128, 128, 8,  false>(w5, bP, 128, ps, bias_l + 416, bQ);
            rstage<128, 128, 8,  true >(w6, bQ, 128, ps, bias_l + 544, bP);
            // S7 partials + prefetch next batch's xc
#pragma unroll
            for (int r = 0; r < 8; ++r) {
                const float x0 = bP[r * 128 + 2 * o7], x1 = bP[r * 128 + 2 * o7 + 1];
                ps[r * 1024 + o7 * 16 + jb7]     = x0 * w7[0] + x1 * w7[1];
                ps[r * 1024 + o7 * 16 + jb7 + 8] = x0 * w7[2] + x1 * w7[3];
            }
            if (rb < 3) stage_xc(xc, pu, hlast, n0, rb + 1);
            __syncthreads();
            if (T < 128) {
                const int r = T >> 4, j = T & 15;
                float s = bias_l[672 + j];
#pragma unroll
                for (int o2 = 0; o2 < 64; ++o2) s += ps[r * 1024 + o2 * 16 + j];
                const int trow = t0 + rb * 8 + r;
                const float yv = y_g[((size_t)b * YDIM + j) * TT + trow];
                const float d = s - yv;
                lossreg += d * d;
            }
            // loop-top barrier closes this batch
        }
    }
    __syncthreads();
#pragma unroll
    for (int off = 32; off > 0; off >>= 1) lossreg += __shfl_down(lossreg, off, 64);
    if ((T & 63) == 0) red[T >> 6] = lossreg;
    __syncthreads();
    if (T == 0) {
        float s = 0.f;
#pragma unroll
        for (int i = 0; i < 8; ++i) s += red[i];
        atomicAdd(out, s);
    }
}

__global__ void zero_out_kernel(float* o) { o[0] = 0.f; }

extern "C" void kernel_launch(void* const* d_in, const int* in_sizes, int n_in,
                              void* d_out, int out_size, void* d_ws, size_t ws_size,
                              hipStream_t stream)
{
    (void)in_sizes; (void)n_in; (void)out_size;
    const float* u    = (const float*)d_in[0];
    const float* y    = (const float*)d_in[1];
    const float* h0   = (const float*)d_in[2];
    const float* puw1 = (const float*)d_in[3];
    const float* pub1 = (const float*)d_in[4];
    const float* puw2 = (const float*)d_in[5];
    const float* pub2 = (const float*)d_in[6];
    const float* dw1  = (const float*)d_in[7];
    const float* db1  = (const float*)d_in[8];
    const float* dw2  = (const float*)d_in[9];
    const float* db2  = (const float*)d_in[10];
    const float* xw   = (const float*)d_in[11];
    const float* xbi  = (const float*)d_in[12];
    const float* pxw1 = (const float*)d_in[13];
    const float* pxb1 = (const float*)d_in[14];
    const float* pxw2 = (const float*)d_in[15];
    const float* pxb2 = (const float*)d_in[16];
    const float* mw1  = (const float*)d_in[17];
    const float* mb1  = (const float*)d_in[18];
    const float* mw2  = (const float*)d_in[19];
    const float* mb2  = (const float*)d_in[20];
    const float* gwih = (const float*)d_in[21];
    const float* gwhh = (const float*)d_in[22];

    const size_t per_sample = (size_t)TT * HH * 2 * 2;   // pu + traj (bf16)
    int C = BB;
    while (C > 1 && (size_t)C * per_sample > ws_size) C >>= 1;
    bf16* puB = (bf16*)d_ws;
    bf16* trB = puB + (size_t)C * TT * HH;   // pass-B out aliases its in (safe)

    zero_out_kernel<<<1, 1, 0, stream>>>((float*)d_out);
    for (int s0 = 0; s0 < BB; s0 += C) {
        phi_u_kernel<<<512, 512, 0, stream>>>(u, puw1, pub1, puw2, pub2, puB, s0, C * TT);
        gru_pass_kernel<<<C, 512, 0, stream>>>(puB, gwih, gwhh, h0, trB, 0, s0);
        gru_pass_kernel<<<C, 512, 0, stream>>>(trB, gwih + H3 * HH, gwhh + H3 * HH,
                                               h0 + BB * HH, trB, 1, s0);
        head_kernel<<<512, 512, 0, stream>>>(puB, trB, y,
                                             dw1, db1, dw2, db2, xw, xbi,
                                             pxw1, pxb1, pxw2, pxb2,
                                             mw1, mb1, mw2, mb2,
                                             (float*)d_out, s0, C * TT);
    }
}

// Round 11
// 6045.333 us; speedup vs baseline: 5.7703x; 1.3429x over previous
//
#include <hip/hip_runtime.h>
#include <hip/hip_bf16.h>

#define TT 2048
#define BB 256
#define HH 128
#define UDIM 16
#define YDIM 16
#define ZDIM 32
#define H3 384

typedef __hip_bfloat16 bf16;
typedef _Float16 half2v __attribute__((ext_vector_type(2)));

constexpr int clog2(int x) { return x <= 1 ? 0 : 1 + clog2(x >> 1); }

// ---------------------------------------------------------------------------
// Register-weight linear stage (phi_u + head).
// ---------------------------------------------------------------------------
template <int M_, int K_, int O_, bool RELU_>
__device__ __forceinline__ void rstage(const float* __restrict__ wfrag,
                                       const float* __restrict__ xin, int XS,
                                       float* __restrict__ ps,
                                       const float* __restrict__ bias,
                                       float* __restrict__ outb)
{
    constexpr int F = K_ / O_;
    const int T = threadIdx.x;
    const int jb = T & (M_ / 2 - 1);
    const int o  = T >> clog2(M_ / 2);
#pragma unroll
    for (int r = 0; r < 8; ++r) {
        float a0 = 0.f, a1 = 0.f;
#pragma unroll
        for (int g = 0; g < F; g += 4) {
            const float4 xv = *reinterpret_cast<const float4*>(&xin[r * XS + o * F + g]);
            a0 += xv.x * wfrag[g]     + xv.y * wfrag[g + 1]
                + xv.z * wfrag[g + 2] + xv.w * wfrag[g + 3];
            a1 += xv.x * wfrag[F + g]     + xv.y * wfrag[F + g + 1]
                + xv.z * wfrag[F + g + 2] + xv.w * wfrag[F + g + 3];
        }
        ps[r * 1024 + o * M_ + jb]           = a0;
        ps[r * 1024 + o * M_ + jb + M_ / 2]  = a1;
    }
    __syncthreads();
    for (int oi = T; oi < 8 * M_; oi += 512) {
        const int r = oi >> clog2(M_);
        const int j = oi & (M_ - 1);
        float s = bias[j];
#pragma unroll
        for (int o2 = 0; o2 < O_; ++o2) s += ps[r * 1024 + o2 * M_ + j];
        if (RELU_) s = fmaxf(s, 0.f);
        outb[r * M_ + j] = s;
    }
    __syncthreads();
}

template <int M_, int K_, int O_>
__device__ __forceinline__ void loadw(float* __restrict__ wfrag, const float* __restrict__ Wg)
{
    constexpr int F = K_ / O_;
    const int T = threadIdx.x;
    const int jb = T & (M_ / 2 - 1);
    const int o  = T >> clog2(M_ / 2);
#pragma unroll
    for (int h = 0; h < 2; ++h)
#pragma unroll
        for (int g = 0; g < F; g += 4)
            *reinterpret_cast<float4*>(&wfrag[h * F + g]) =
                *reinterpret_cast<const float4*>(&Wg[(jb + h * (M_ / 2)) * K_ + o * F + g]);
}

// ---------------------------------------------------------------------------
// phi_u: register weights, persistent 512 blocks (unchanged).
// ---------------------------------------------------------------------------
__global__ __launch_bounds__(512, 2) void phi_u_kernel(
    const float* __restrict__ u, const float* __restrict__ w1, const float* __restrict__ b1,
    const float* __restrict__ w2, const float* __restrict__ b2,
    bf16* __restrict__ pu, int s0, int nrows)
{
    __shared__ __align__(16) float ps[8192];
    __shared__ __align__(16) float xc[8 * 16];
    __shared__ __align__(16) float bP[8 * 128];
    __shared__ __align__(16) float bias_l[256];
    const int T = threadIdx.x;
    if (T < 128) { bias_l[T] = b1[T]; bias_l[128 + T] = b2[T]; }
    const int jb = T & 63, o = T >> 6;
    float wa[4];
    wa[0] = w1[jb * 16 + o * 2];        wa[1] = w1[jb * 16 + o * 2 + 1];
    wa[2] = w1[(jb + 64) * 16 + o * 2]; wa[3] = w1[(jb + 64) * 16 + o * 2 + 1];
    float wb[32]; loadw<128, 128, 8>(wb, w2);
    __syncthreads();

    for (int tile = blockIdx.x; tile < nrows / 32; tile += gridDim.x) {
        const int n0 = tile * 32;
        const int b  = s0 + (n0 >> 11);
        const int t0 = n0 & (TT - 1);
#pragma unroll 1
        for (int rb = 0; rb < 4; ++rb) {
            if (T < 128) {
                const int r = T & 7, c = T >> 3;
                xc[r * 16 + c] = u[((size_t)b * UDIM + c) * TT + t0 + rb * 8 + r];
            }
            __syncthreads();
#pragma unroll
            for (int r = 0; r < 8; ++r) {
                const float x0 = xc[r * 16 + o * 2], x1 = xc[r * 16 + o * 2 + 1];
                ps[r * 1024 + o * 128 + jb]      = x0 * wa[0] + x1 * wa[1];
                ps[r * 1024 + o * 128 + jb + 64] = x0 * wa[2] + x1 * wa[3];
            }
            __syncthreads();
            for (int oi = T; oi < 8 * 128; oi += 512) {
                const int r = oi >> 7, j = oi & 127;
                float s = bias_l[j];
#pragma unroll
                for (int o2 = 0; o2 < 8; ++o2) s += ps[r * 1024 + o2 * 128 + j];
                bP[r * 128 + j] = fmaxf(s, 0.f);
            }
            __syncthreads();
            rstage<128, 128, 8, false>(wb, bP, 128, ps, bias_l + 128, bP);
            const int row0 = n0 + rb * 8;
            for (int oi = T; oi < 8 * 128; oi += 512) {
                const int r = oi >> 7, j = oi & 127;
                pu[(size_t)(row0 + r) * HH + j] = __float2bfloat16(bP[r * 128 + j]);
            }
            __syncthreads();
        }
    }
}

// ---------------------------------------------------------------------------
// Fused 2-layer GRU, one block/sample, 1024 threads (16 waves).
// f16 weights (96 half2 VGPRs/thread) keep VGPR <= 128 cap for 16-wave block.
// Skew: threads 0-511 = layer 0 at step i; 512-1023 = layer 1 at step i-1.
// Per layer: wave g=t>>6 -> matrix m=g>>2, slice o=g&3; lane u=t&63 owns rows
// u+64i (i<6): 96 fdot2 per step from 4 broadcast b128 reads of half2 slices.
// Partials ps[L*3072 + o*768 + m*384 + row] (lane-stride-1, conflict-free).
// Tail (simple round-8 form): threads t<128 of each layer-half assemble gates
// (24 conflict-free scalar reads), keep h state fp32 in registers, write h/x
// to LDS as scalar _Float16. Layer-0 output -> x1h double buffer (layer-1
// input). hlast = layer-1 state ENTERING its step (pre-update).
// ---------------------------------------------------------------------------
__global__ __launch_bounds__(1024, 4) void gru_fused_kernel(
    const bf16* __restrict__ pu_in,   // (C*T, H)
    const float* __restrict__ wih,    // (L, 3H, H)
    const float* __restrict__ whh,    // (L, 3H, H)
    const float* __restrict__ h0_g,   // (L, B, H)
    bf16* __restrict__ hlast,         // (C*T, H)
    int s0)
{
    const int tid = threadIdx.x;
    const int L = tid >> 9;           // wave-uniform layer
    const int t = tid & 511;
    __shared__ __align__(16) _Float16 x0h[HH];        // layer-0 input (f16)
    __shared__ __align__(16) _Float16 x1h[2][HH];     // layer-0 out / layer-1 in
    __shared__ __align__(16) _Float16 h0h[HH];
    __shared__ __align__(16) _Float16 h1h[HH];
    __shared__ __align__(16) float ps[2 * 3072];

    const int g = t >> 6;             // wave-uniform
    const int m = g >> 2, o = g & 3;
    const int u = t & 63;
    const float* Wmat = ((m == 0) ? wih : whh) + (size_t)L * H3 * HH;
    half2v w[6][16];
#pragma unroll
    for (int i = 0; i < 6; ++i) {
        const float* src = &Wmat[(u + 64 * i) * HH + o * 32];
#pragma unroll
        for (int k = 0; k < 16; ++k) {
            half2v v; v.x = (_Float16)src[2 * k]; v.y = (_Float16)src[2 * k + 1];
            w[i][k] = v;
        }
    }
    float* psL = ps + L * 3072;
    const int psb = o * 768 + m * 384 + u;

    const bf16* xb = pu_in + (size_t)blockIdx.x * TT * HH;
    bf16* ob = hlast + (size_t)blockIdx.x * TT * HH;

    float hreg = 0.f;                 // tail threads' fp32 state
    if (tid < HH) {
        hreg = h0_g[(size_t)(s0 + blockIdx.x) * HH + tid];
        h0h[tid] = (_Float16)hreg;
        x0h[tid] = (_Float16)__bfloat162float(xb[tid]);
    } else if (tid >= 512 && tid < 512 + HH) {
        const int j = tid - 512;
        hreg = h0_g[((size_t)BB + s0 + blockIdx.x) * HH + j];
        h1h[j] = (_Float16)hreg;
    }
    __syncthreads();

#pragma unroll 1
    for (int i = 0; i <= TT; ++i) {
        const bool act = (L == 0) ? (i < TT) : (i >= 1);
        float xnext = 0.f;
        if (L == 0 && t < HH && i + 1 < TT)
            xnext = __bfloat162float(xb[(size_t)(i + 1) * HH + t]);   // prefetch
        if (act) {
            const _Float16* vbase;
            if (L == 0) vbase = (m == 0) ? x0h : h0h;
            else        vbase = (m == 0) ? x1h[(i + 1) & 1] : h1h;
            const half2v* vec2 = reinterpret_cast<const half2v*>(vbase) + o * 16;
            float a0 = 0.f, a1 = 0.f, a2 = 0.f, a3 = 0.f, a4 = 0.f, a5 = 0.f;
#pragma unroll
            for (int k4 = 0; k4 < 4; ++k4) {
                half2v xt[4];
                *reinterpret_cast<float4*>(xt) = reinterpret_cast<const float4*>(vec2)[k4];
#pragma unroll
                for (int e = 0; e < 4; ++e) {
                    const int k = k4 * 4 + e;
                    a0 = __builtin_amdgcn_fdot2(xt[e], w[0][k], a0, false);
                    a1 = __builtin_amdgcn_fdot2(xt[e], w[1][k], a1, false);
                    a2 = __builtin_amdgcn_fdot2(xt[e], w[2][k], a2, false);
                    a3 = __builtin_amdgcn_fdot2(xt[e], w[3][k], a3, false);
                    a4 = __builtin_amdgcn_fdot2(xt[e], w[4][k], a4, false);
                    a5 = __builtin_amdgcn_fdot2(xt[e], w[5][k], a5, false);
                }
            }
            psL[psb]       = a0; psL[psb + 64]  = a1; psL[psb + 128] = a2;
            psL[psb + 192] = a3; psL[psb + 256] = a4; psL[psb + 320] = a5;
        }
        __syncthreads();   // ps ready; all LDS vec reads of this iter done
        if (t < HH && act) {
            const int j = t;
            float gir = 0.f, giz = 0.f, gin = 0.f, ghr = 0.f, ghz = 0.f, ghn = 0.f;
#pragma unroll
            for (int o2 = 0; o2 < 4; ++o2) {
                const float* pp = psL + o2 * 768;
                gir += pp[j];        giz += pp[128 + j]; gin += pp[256 + j];
                ghr += pp[384 + j];  ghz += pp[512 + j]; ghn += pp[640 + j];
            }
            const float rg = 1.f / (1.f + __expf(-(gir + ghr)));
            const float zg = 1.f / (1.f + __expf(-(giz + ghz)));
            const float narg = gin + rg * ghn;
            const float e2 = __expf(2.f * fabsf(narg));
            float ng = 1.f - 2.f / (e2 + 1.f);          // |tanh|, inf-safe
            ng = (narg < 0.f) ? -ng : ng;
            const float hn = (1.f - zg) * ng + zg * hreg;
            if (L == 0) {
                h0h[j] = (_Float16)hn;
                x1h[i & 1][j] = (_Float16)hn;           // layer-1 input for step i
                x0h[j] = (_Float16)xnext;
            } else {
                ob[(size_t)(i - 1) * HH + j] = __float2bfloat16(hreg);  // pre-update
                h1h[j] = (_Float16)hn;
            }
            hreg = hn;
        }
        __syncthreads();   // h/x updated for next iteration
    }
}

// ---------------------------------------------------------------------------
// head: round-6 version — all weights in registers, S7 via LDS partials.
// ---------------------------------------------------------------------------
__device__ __forceinline__ void stage_xc(float* __restrict__ xc,
                                         const bf16* __restrict__ pu,
                                         const bf16* __restrict__ hl,
                                         int n0, int rb)
{
    const int T = threadIdx.x;
    const int base = n0 + rb * 8;
#pragma unroll
    for (int i = 0; i < 4; ++i) {
        const int idx = T + i * 512;
        const int r = idx >> 8, k = idx & 255;
        const size_t row = (size_t)(base + r);
        xc[r * 256 + k] = (k < 128) ? __bfloat162float(pu[row * HH + k])
                                    : __bfloat162float(hl[row * HH + (k - 128)]);
    }
}

__global__ __launch_bounds__(512, 2) void head_kernel(
    const bf16* __restrict__ pu, const bf16* __restrict__ hlast, const float* __restrict__ y_g,
    const float* __restrict__ dw1, const float* __restrict__ db1,
    const float* __restrict__ dw2, const float* __restrict__ db2,
    const float* __restrict__ xw, const float* __restrict__ xb,
    const float* __restrict__ pxw1, const float* __restrict__ pxb1,
    const float* __restrict__ pxw2, const float* __restrict__ pxb2,
    const float* __restrict__ mw1, const float* __restrict__ mb1,
    const float* __restrict__ mw2, const float* __restrict__ mb2,
    float* __restrict__ out, int s0, int nrows)
{
    __shared__ __align__(16) float ps[8192];
    __shared__ __align__(16) float xc[8 * 256];
    __shared__ __align__(16) float bP[8 * 128];
    __shared__ __align__(16) float bQ[8 * 128];
    __shared__ __align__(16) float bX[8 * 32];
    __shared__ __align__(16) float bias_l[688];
    __shared__ float red[8];
    const int T = threadIdx.x;

    if (T < 128) bias_l[T]       = db1[T];
    if (T < 128) bias_l[128 + T] = db2[T];
    if (T < 32)  bias_l[256 + T] = xb[T];
    if (T < 128) bias_l[288 + T] = pxb1[T];
    if (T < 128) bias_l[416 + T] = pxb2[T];
    if (T < 128) bias_l[544 + T] = mb1[T];
    if (T < 16)  bias_l[672 + T] = mb2[T];

    float w1[64]; loadw<128, 256, 8 >(w1, dw1);
    float w2[32]; loadw<128, 128, 8 >(w2, dw2);
    float w3[8];  loadw<32,  128, 32>(w3, xw);
    float w4[8];  loadw<128, 32,  8 >(w4, pxw1);
    float w5[32]; loadw<128, 128, 8 >(w5, pxw2);
    float w6[32]; loadw<128, 128, 8 >(w6, mw1);
    const int jb7 = T & 7, o7 = T >> 3;   // S7: M=16,K=128,O=64,F=2
    float w7[4];
    w7[0] = mw2[jb7 * 128 + 2 * o7];       w7[1] = mw2[jb7 * 128 + 2 * o7 + 1];
    w7[2] = mw2[(jb7 + 8) * 128 + 2 * o7]; w7[3] = mw2[(jb7 + 8) * 128 + 2 * o7 + 1];

    float lossreg = 0.f;

    for (int tile = blockIdx.x; tile < nrows / 32; tile += gridDim.x) {
        const int n0 = tile * 32;
        const int b  = s0 + (n0 >> 11);
        const int t0 = n0 & (TT - 1);
        stage_xc(xc, pu, hlast, n0, 0);
#pragma unroll 1
        for (int rb = 0; rb < 4; ++rb) {
            __syncthreads();   // xc ready; ps free from previous batch
            rstage<128, 256, 8,  true >(w1, xc, 256, ps, bias_l + 0,   bP);
            rstage<128, 128, 8,  false>(w2, bP, 128, ps, bias_l + 128, bQ);
            rstage<32,  128, 32, false>(w3, bQ, 128, ps, bias_l + 256, bX);
            rstage<128, 32,  8,  true >(w4, bX, 32,  ps, bias_l + 288, bP);
            rstage<128, 128, 8,  false>(w5, bP, 128, ps, bias_l + 416, bQ);
            rstage<128, 128, 8,  true >(w6, bQ, 128, ps, bias_l + 544, bP);
            // S7 partials + prefetch next batch's xc
#pragma unroll
            for (int r = 0; r < 8; ++r) {
                const float x0 = bP[r * 128 + 2 * o7], x1 = bP[r * 128 + 2 * o7 + 1];
                ps[r * 1024 + o7 * 16 + jb7]     = x0 * w7[0] + x1 * w7[1];
                ps[r * 1024 + o7 * 16 + jb7 + 8] = x0 * w7[2] + x1 * w7[3];
            }
            if (rb < 3) stage_xc(xc, pu, hlast, n0, rb + 1);
            __syncthreads();
            if (T < 128) {
                const int r = T >> 4, j = T & 15;
                float s = bias_l[672 + j];
#pragma unroll
                for (int o2 = 0; o2 < 64; ++o2) s += ps[r * 1024 + o2 * 16 + j];
                const int trow = t0 + rb * 8 + r;
                const float yv = y_g[((size_t)b * YDIM + j) * TT + trow];
                const float d = s - yv;
                lossreg += d * d;
            }
            // loop-top barrier closes this batch
        }
    }
    __syncthreads();
#pragma unroll
    for (int off = 32; off > 0; off >>= 1) lossreg += __shfl_down(lossreg, off, 64);
    if ((T & 63) == 0) red[T >> 6] = lossreg;
    __syncthreads();
    if (T == 0) {
        float s = 0.f;
#pragma unroll
        for (int i = 0; i < 8; ++i) s += red[i];
        atomicAdd(out, s);
    }
}

__global__ void zero_out_kernel(float* o) { o[0] = 0.f; }

extern "C" void kernel_launch(void* const* d_in, const int* in_sizes, int n_in,
                              void* d_out, int out_size, void* d_ws, size_t ws_size,
                              hipStream_t stream)
{
    (void)in_sizes; (void)n_in; (void)out_size;
    const float* u    = (const float*)d_in[0];
    const float* y    = (const float*)d_in[1];
    const float* h0   = (const float*)d_in[2];
    const float* puw1 = (const float*)d_in[3];
    const float* pub1 = (const float*)d_in[4];
    const float* puw2 = (const float*)d_in[5];
    const float* pub2 = (const float*)d_in[6];
    const float* dw1  = (const float*)d_in[7];
    const float* db1  = (const float*)d_in[8];
    const float* dw2  = (const float*)d_in[9];
    const float* db2  = (const float*)d_in[10];
    const float* xw   = (const float*)d_in[11];
    const float* xbi  = (const float*)d_in[12];
    const float* pxw1 = (const float*)d_in[13];
    const float* pxb1 = (const float*)d_in[14];
    const float* pxw2 = (const float*)d_in[15];
    const float* pxb2 = (const float*)d_in[16];
    const float* mw1  = (const float*)d_in[17];
    const float* mb1  = (const float*)d_in[18];
    const float* mw2  = (const float*)d_in[19];
    const float* mb2  = (const float*)d_in[20];
    const float* gwih = (const float*)d_in[21];
    const float* gwhh = (const float*)d_in[22];

    const size_t per_sample = (size_t)TT * HH * 2 * 2;   // pu + hlast (bf16)
    int C = BB;
    while (C > 1 && (size_t)C * per_sample > ws_size) C >>= 1;
    bf16* puB = (bf16*)d_ws;
    bf16* hlB = puB + (size_t)C * TT * HH;

    zero_out_kernel<<<1, 1, 0, stream>>>((float*)d_out);
    for (int s0 = 0; s0 < BB; s0 += C) {
        phi_u_kernel<<<512, 512, 0, stream>>>(u, puw1, pub1, puw2, pub2, puB, s0, C * TT);
        gru_fused_kernel<<<C, 1024, 0, stream>>>(puB, gwih, gwhh, h0, hlB, s0);
        head_kernel<<<512, 512, 0, stream>>>(puB, hlB, y,
                                             dw1, db1, dw2, db2, xw, xbi,
                                             pxw1, pxb1, pxw2, pxb2,
                                             mw1, mb1, mw2, mb2,
                                             (float*)d_out, s0, C * TT);
    }
}

// Round 12
// 4888.475 us; speedup vs baseline: 7.1359x; 1.2367x over previous
//
#include <hip/hip_runtime.h>
#include <hip/hip_bf16.h>

#define TT 2048
#define BB 256
#define HH 128
#define UDIM 16
#define YDIM 16
#define ZDIM 32
#define H3 384

typedef __hip_bfloat16 bf16;
typedef _Float16 half2v __attribute__((ext_vector_type(2)));

constexpr int clog2(int x) { return x <= 1 ? 0 : 1 + clog2(x >> 1); }

// ---------------------------------------------------------------------------
// f32 register-weight linear stage (phi_u only).
// ---------------------------------------------------------------------------
template <int M_, int K_, int O_, bool RELU_>
__device__ __forceinline__ void rstage(const float* __restrict__ wfrag,
                                       const float* __restrict__ xin, int XS,
                                       float* __restrict__ ps,
                                       const float* __restrict__ bias,
                                       float* __restrict__ outb)
{
    constexpr int F = K_ / O_;
    const int T = threadIdx.x;
    const int jb = T & (M_ / 2 - 1);
    const int o  = T >> clog2(M_ / 2);
#pragma unroll
    for (int r = 0; r < 8; ++r) {
        float a0 = 0.f, a1 = 0.f;
#pragma unroll
        for (int g = 0; g < F; g += 4) {
            const float4 xv = *reinterpret_cast<const float4*>(&xin[r * XS + o * F + g]);
            a0 += xv.x * wfrag[g]     + xv.y * wfrag[g + 1]
                + xv.z * wfrag[g + 2] + xv.w * wfrag[g + 3];
            a1 += xv.x * wfrag[F + g]     + xv.y * wfrag[F + g + 1]
                + xv.z * wfrag[F + g + 2] + xv.w * wfrag[F + g + 3];
        }
        ps[r * 1024 + o * M_ + jb]           = a0;
        ps[r * 1024 + o * M_ + jb + M_ / 2]  = a1;
    }
    __syncthreads();
    for (int oi = T; oi < 8 * M_; oi += 512) {
        const int r = oi >> clog2(M_);
        const int j = oi & (M_ - 1);
        float s = bias[j];
#pragma unroll
        for (int o2 = 0; o2 < O_; ++o2) s += ps[r * 1024 + o2 * M_ + j];
        if (RELU_) s = fmaxf(s, 0.f);
        outb[r * M_ + j] = s;
    }
    __syncthreads();
}

template <int M_, int K_, int O_>
__device__ __forceinline__ void loadw(float* __restrict__ wfrag, const float* __restrict__ Wg)
{
    constexpr int F = K_ / O_;
    const int T = threadIdx.x;
    const int jb = T & (M_ / 2 - 1);
    const int o  = T >> clog2(M_ / 2);
#pragma unroll
    for (int h = 0; h < 2; ++h)
#pragma unroll
        for (int g = 0; g < F; g += 4)
            *reinterpret_cast<float4*>(&wfrag[h * F + g]) =
                *reinterpret_cast<const float4*>(&Wg[(jb + h * (M_ / 2)) * K_ + o * F + g]);
}

// f16 variants (head): wfrag = F half2 (2 rows x F/2), xin f16 LDS, XS in halves.
template <int M_, int K_, int O_>
__device__ __forceinline__ void loadw_h(half2v* __restrict__ wfrag, const float* __restrict__ Wg)
{
    constexpr int F = K_ / O_;
    const int T = threadIdx.x;
    const int jb = T & (M_ / 2 - 1);
    const int o  = T >> clog2(M_ / 2);
#pragma unroll
    for (int h = 0; h < 2; ++h)
#pragma unroll
        for (int g = 0; g < F / 2; ++g) {
            const float* s = &Wg[(jb + h * (M_ / 2)) * K_ + o * F + 2 * g];
            half2v v; v.x = (_Float16)s[0]; v.y = (_Float16)s[1];
            wfrag[h * (F / 2) + g] = v;
        }
}

template <int M_, int K_, int O_, bool RELU_>
__device__ __forceinline__ void rstage_h(const half2v* __restrict__ wfrag,
                                         const _Float16* __restrict__ xin, int XS,
                                         float* __restrict__ ps,
                                         const float* __restrict__ bias,
                                         _Float16* __restrict__ outb)
{
    constexpr int F = K_ / O_;
    constexpr int FH = F / 2;
    const int T = threadIdx.x;
    const int jb = T & (M_ / 2 - 1);
    const int o  = T >> clog2(M_ / 2);
#pragma unroll
    for (int r = 0; r < 8; ++r) {
        float a0 = 0.f, a1 = 0.f;
        const half2v* xv = reinterpret_cast<const half2v*>(xin + r * XS + o * F);
        if constexpr (FH >= 4) {
#pragma unroll
            for (int g4 = 0; g4 < FH / 4; ++g4) {
                half2v xt[4];
                *reinterpret_cast<float4*>(xt) = reinterpret_cast<const float4*>(xv)[g4];
#pragma unroll
                for (int e = 0; e < 4; ++e) {
                    a0 = __builtin_amdgcn_fdot2(xt[e], wfrag[g4 * 4 + e], a0, false);
                    a1 = __builtin_amdgcn_fdot2(xt[e], wfrag[FH + g4 * 4 + e], a1, false);
                }
            }
        } else {   // FH == 2
            half2v xt[2];
            *reinterpret_cast<float2*>(xt) = *reinterpret_cast<const float2*>(xv);
            a0 = __builtin_amdgcn_fdot2(xt[0], wfrag[0], a0, false);
            a0 = __builtin_amdgcn_fdot2(xt[1], wfrag[1], a0, false);
            a1 = __builtin_amdgcn_fdot2(xt[0], wfrag[FH], a1, false);
            a1 = __builtin_amdgcn_fdot2(xt[1], wfrag[FH + 1], a1, false);
        }
        ps[r * 1024 + o * M_ + jb]           = a0;
        ps[r * 1024 + o * M_ + jb + M_ / 2]  = a1;
    }
    __syncthreads();
    for (int oi = T; oi < 8 * M_; oi += 512) {
        const int r = oi >> clog2(M_);
        const int j = oi & (M_ - 1);
        float s = bias[j];
#pragma unroll
        for (int o2 = 0; o2 < O_; ++o2) s += ps[r * 1024 + o2 * M_ + j];
        if (RELU_) s = fmaxf(s, 0.f);
        outb[r * M_ + j] = (_Float16)s;
    }
    __syncthreads();
}

// ---------------------------------------------------------------------------
// phi_u: register weights, persistent 512 blocks (unchanged).
// ---------------------------------------------------------------------------
__global__ __launch_bounds__(512, 2) void phi_u_kernel(
    const float* __restrict__ u, const float* __restrict__ w1, const float* __restrict__ b1,
    const float* __restrict__ w2, const float* __restrict__ b2,
    bf16* __restrict__ pu, int s0, int nrows)
{
    __shared__ __align__(16) float ps[8192];
    __shared__ __align__(16) float xc[8 * 16];
    __shared__ __align__(16) float bP[8 * 128];
    __shared__ __align__(16) float bias_l[256];
    const int T = threadIdx.x;
    if (T < 128) { bias_l[T] = b1[T]; bias_l[128 + T] = b2[T]; }
    const int jb = T & 63, o = T >> 6;
    float wa[4];
    wa[0] = w1[jb * 16 + o * 2];        wa[1] = w1[jb * 16 + o * 2 + 1];
    wa[2] = w1[(jb + 64) * 16 + o * 2]; wa[3] = w1[(jb + 64) * 16 + o * 2 + 1];
    float wb[32]; loadw<128, 128, 8>(wb, w2);
    __syncthreads();

    for (int tile = blockIdx.x; tile < nrows / 32; tile += gridDim.x) {
        const int n0 = tile * 32;
        const int b  = s0 + (n0 >> 11);
        const int t0 = n0 & (TT - 1);
#pragma unroll 1
        for (int rb = 0; rb < 4; ++rb) {
            if (T < 128) {
                const int r = T & 7, c = T >> 3;
                xc[r * 16 + c] = u[((size_t)b * UDIM + c) * TT + t0 + rb * 8 + r];
            }
            __syncthreads();
#pragma unroll
            for (int r = 0; r < 8; ++r) {
                const float x0 = xc[r * 16 + o * 2], x1 = xc[r * 16 + o * 2 + 1];
                ps[r * 1024 + o * 128 + jb]      = x0 * wa[0] + x1 * wa[1];
                ps[r * 1024 + o * 128 + jb + 64] = x0 * wa[2] + x1 * wa[3];
            }
            __syncthreads();
            for (int oi = T; oi < 8 * 128; oi += 512) {
                const int r = oi >> 7, j = oi & 127;
                float s = bias_l[j];
#pragma unroll
                for (int o2 = 0; o2 < 8; ++o2) s += ps[r * 1024 + o2 * 128 + j];
                bP[r * 128 + j] = fmaxf(s, 0.f);
            }
            __syncthreads();
            rstage<128, 128, 8, false>(wb, bP, 128, ps, bias_l + 128, bP);
            const int row0 = n0 + rb * 8;
            for (int oi = T; oi < 8 * 128; oi += 512) {
                const int r = oi >> 7, j = oi & 127;
                pu[(size_t)(row0 + r) * HH + j] = __float2bfloat16(bP[r * 128 + j]);
            }
            __syncthreads();
        }
    }
}

// ---------------------------------------------------------------------------
// Fused 2-layer GRU, 512 threads: each thread does BOTH layers' matvec slices
// (192 half2 weight regs, fits 256-VGPR class -> no AGPR-copy tax).
// Skew: L0 at step i (threads' wA), L1 at step i-1 (wB). Wave g=t>>6 ->
// m=g>>2, o=g&3; lane u owns rows u+64i (i<6). Partials psA/psB
// [o*768+m*384+row] lane-stride-1 conflict-free. Tails: threads 0-127 = L0
// gates, 128-255 = L1 gates (parallel waves). 2 barriers/iter for both layers.
// ---------------------------------------------------------------------------
__device__ __forceinline__ void gmv(const half2v w[6][16], const _Float16* __restrict__ vb,
                                    int o, float* __restrict__ psL, int psb)
{
    const half2v* vec2 = reinterpret_cast<const half2v*>(vb) + o * 16;
    float a0 = 0.f, a1 = 0.f, a2 = 0.f, a3 = 0.f, a4 = 0.f, a5 = 0.f;
#pragma unroll
    for (int k4 = 0; k4 < 4; ++k4) {
        half2v xt[4];
        *reinterpret_cast<float4*>(xt) = reinterpret_cast<const float4*>(vec2)[k4];
#pragma unroll
        for (int e = 0; e < 4; ++e) {
            const int k = k4 * 4 + e;
            a0 = __builtin_amdgcn_fdot2(xt[e], w[0][k], a0, false);
            a1 = __builtin_amdgcn_fdot2(xt[e], w[1][k], a1, false);
            a2 = __builtin_amdgcn_fdot2(xt[e], w[2][k], a2, false);
            a3 = __builtin_amdgcn_fdot2(xt[e], w[3][k], a3, false);
            a4 = __builtin_amdgcn_fdot2(xt[e], w[4][k], a4, false);
            a5 = __builtin_amdgcn_fdot2(xt[e], w[5][k], a5, false);
        }
    }
    psL[psb]       = a0; psL[psb + 64]  = a1; psL[psb + 128] = a2;
    psL[psb + 192] = a3; psL[psb + 256] = a4; psL[psb + 320] = a5;
}

__global__ __launch_bounds__(512, 2) void gru_fused_kernel(
    const bf16* __restrict__ pu_in,   // (C*T, H)
    const float* __restrict__ wih,    // (L, 3H, H)
    const float* __restrict__ whh,    // (L, 3H, H)
    const float* __restrict__ h0_g,   // (L, B, H)
    bf16* __restrict__ hlast,         // (C*T, H)
    int s0)
{
    const int t = threadIdx.x;
    __shared__ __align__(16) _Float16 x0h[HH];
    __shared__ __align__(16) _Float16 x1h[2][HH];
    __shared__ __align__(16) _Float16 h0h[HH];
    __shared__ __align__(16) _Float16 h1h[HH];
    __shared__ __align__(16) float ps[2 * 3072];

    const int g = t >> 6;             // wave-uniform
    const int m = g >> 2, o = g & 3;
    const int u = t & 63;
    const float* WbaseA = ((m == 0) ? wih : whh);
    const float* WbaseB = WbaseA + (size_t)H3 * HH;
    half2v wA[6][16], wB[6][16];
#pragma unroll
    for (int i = 0; i < 6; ++i) {
        const float* sA = &WbaseA[(u + 64 * i) * HH + o * 32];
        const float* sB = &WbaseB[(u + 64 * i) * HH + o * 32];
#pragma unroll
        for (int k = 0; k < 16; ++k) {
            half2v v; v.x = (_Float16)sA[2 * k]; v.y = (_Float16)sA[2 * k + 1];
            wA[i][k] = v;
            half2v w2; w2.x = (_Float16)sB[2 * k]; w2.y = (_Float16)sB[2 * k + 1];
            wB[i][k] = w2;
        }
    }
    float* psA = ps;
    float* psB = ps + 3072;
    const int psb = o * 768 + m * 384 + u;

    const bf16* xb = pu_in + (size_t)blockIdx.x * TT * HH;
    bf16* ob = hlast + (size_t)blockIdx.x * TT * HH;

    float hreg = 0.f;                 // t<128: L0 state[j=t]; t in [128,256): L1 state[j=t-128]
    if (t < HH) {
        hreg = h0_g[(size_t)(s0 + blockIdx.x) * HH + t];
        h0h[t] = (_Float16)hreg;
        x0h[t] = (_Float16)__bfloat162float(xb[t]);
    } else if (t < 2 * HH) {
        const int j = t - HH;
        hreg = h0_g[((size_t)BB + s0 + blockIdx.x) * HH + j];
        h1h[j] = (_Float16)hreg;
    }
    __syncthreads();

#pragma unroll 1
    for (int i = 0; i <= TT; ++i) {
        float xnext = 0.f;
        if (t < HH && i + 1 < TT)
            xnext = __bfloat162float(xb[(size_t)(i + 1) * HH + t]);   // prefetch for L0
        if (i < TT)  gmv(wA, (m == 0) ? x0h : h0h, o, psA, psb);
        if (i >= 1)  gmv(wB, (m == 0) ? x1h[(i + 1) & 1] : h1h, o, psB, psb);
        __syncthreads();   // ps ready; all LDS vec reads done
        if (t < HH) {
            if (i < TT) {
                const int j = t;
                float gir = 0.f, giz = 0.f, gin = 0.f, ghr = 0.f, ghz = 0.f, ghn = 0.f;
#pragma unroll
                for (int o2 = 0; o2 < 4; ++o2) {
                    const float* pp = psA + o2 * 768;
                    gir += pp[j];        giz += pp[128 + j]; gin += pp[256 + j];
                    ghr += pp[384 + j];  ghz += pp[512 + j]; ghn += pp[640 + j];
                }
                const float rg = 1.f / (1.f + __expf(-(gir + ghr)));
                const float zg = 1.f / (1.f + __expf(-(giz + ghz)));
                const float narg = gin + rg * ghn;
                const float e2 = __expf(2.f * fabsf(narg));
                float ng = 1.f - 2.f / (e2 + 1.f);
                ng = (narg < 0.f) ? -ng : ng;
                const float hn = (1.f - zg) * ng + zg * hreg;
                h0h[j] = (_Float16)hn;
                x1h[i & 1][j] = (_Float16)hn;   // L1 input for step i
                x0h[j] = (_Float16)xnext;
                hreg = hn;
            }
        } else if (t < 2 * HH) {
            if (i >= 1) {
                const int j = t - HH;
                float gir = 0.f, giz = 0.f, gin = 0.f, ghr = 0.f, ghz = 0.f, ghn = 0.f;
#pragma unroll
                for (int o2 = 0; o2 < 4; ++o2) {
                    const float* pp = psB + o2 * 768;
                    gir += pp[j];        giz += pp[128 + j]; gin += pp[256 + j];
                    ghr += pp[384 + j];  ghz += pp[512 + j]; ghn += pp[640 + j];
                }
                const float rg = 1.f / (1.f + __expf(-(gir + ghr)));
                const float zg = 1.f / (1.f + __expf(-(giz + ghz)));
                const float narg = gin + rg * ghn;
                const float e2 = __expf(2.f * fabsf(narg));
                float ng = 1.f - 2.f / (e2 + 1.f);
                ng = (narg < 0.f) ? -ng : ng;
                ob[(size_t)(i - 1) * HH + j] = __float2bfloat16(hreg);  // pre-update
                const float hn = (1.f - zg) * ng + zg * hreg;
                h1h[j] = (_Float16)hn;
                hreg = hn;
            }
        }
        __syncthreads();   // h/x updated for next iteration
    }
}

// ---------------------------------------------------------------------------
// head v3: f16 dot2 stages, weights as half2 registers (~90), f16 LDS buffers.
// S7 via LDS partials (round-6 proven form), now dot2.
// ---------------------------------------------------------------------------
__device__ __forceinline__ void stage_xc_h(_Float16* __restrict__ xc,
                                           const bf16* __restrict__ pu,
                                           const bf16* __restrict__ hl,
                                           int n0, int rb)
{
    const int T = threadIdx.x;
    const int base = n0 + rb * 8;
#pragma unroll
    for (int i = 0; i < 4; ++i) {
        const int idx = T + i * 512;
        const int r = idx >> 8, k = idx & 255;
        const size_t row = (size_t)(base + r);
        xc[r * 256 + k] = (_Float16)((k < 128) ? __bfloat162float(pu[row * HH + k])
                                               : __bfloat162float(hl[row * HH + (k - 128)]));
    }
}

__global__ __launch_bounds__(512, 2) void head_kernel(
    const bf16* __restrict__ pu, const bf16* __restrict__ hlast, const float* __restrict__ y_g,
    const float* __restrict__ dw1, const float* __restrict__ db1,
    const float* __restrict__ dw2, const float* __restrict__ db2,
    const float* __restrict__ xw, const float* __restrict__ xb,
    const float* __restrict__ pxw1, const float* __restrict__ pxb1,
    const float* __restrict__ pxw2, const float* __restrict__ pxb2,
    const float* __restrict__ mw1, const float* __restrict__ mb1,
    const float* __restrict__ mw2, const float* __restrict__ mb2,
    float* __restrict__ out, int s0, int nrows)
{
    __shared__ __align__(16) float ps[8192];
    __shared__ __align__(16) _Float16 xc[8 * 256];
    __shared__ __align__(16) _Float16 bP[8 * 128];
    __shared__ __align__(16) _Float16 bQ[8 * 128];
    __shared__ __align__(16) _Float16 bX[8 * 32];
    __shared__ __align__(16) float bias_l[688];
    __shared__ float red[8];
    const int T = threadIdx.x;

    if (T < 128) bias_l[T]       = db1[T];
    if (T < 128) bias_l[128 + T] = db2[T];
    if (T < 32)  bias_l[256 + T] = xb[T];
    if (T < 128) bias_l[288 + T] = pxb1[T];
    if (T < 128) bias_l[416 + T] = pxb2[T];
    if (T < 128) bias_l[544 + T] = mb1[T];
    if (T < 16)  bias_l[672 + T] = mb2[T];

    half2v w1[32]; loadw_h<128, 256, 8 >(w1, dw1);
    half2v w2[16]; loadw_h<128, 128, 8 >(w2, dw2);
    half2v w3[4];  loadw_h<32,  128, 32>(w3, xw);
    half2v w4[4];  loadw_h<128, 32,  8 >(w4, pxw1);
    half2v w5[16]; loadw_h<128, 128, 8 >(w5, pxw2);
    half2v w6[16]; loadw_h<128, 128, 8 >(w6, mw1);
    const int jb7 = T & 7, o7 = T >> 3;   // S7: M=16,K=128,O=64,F=2
    half2v w7a, w7b;
    w7a.x = (_Float16)mw2[jb7 * 128 + 2 * o7];
    w7a.y = (_Float16)mw2[jb7 * 128 + 2 * o7 + 1];
    w7b.x = (_Float16)mw2[(jb7 + 8) * 128 + 2 * o7];
    w7b.y = (_Float16)mw2[(jb7 + 8) * 128 + 2 * o7 + 1];

    float lossreg = 0.f;

    for (int tile = blockIdx.x; tile < nrows / 32; tile += gridDim.x) {
        const int n0 = tile * 32;
        const int b  = s0 + (n0 >> 11);
        const int t0 = n0 & (TT - 1);
        stage_xc_h(xc, pu, hlast, n0, 0);
#pragma unroll 1
        for (int rb = 0; rb < 4; ++rb) {
            __syncthreads();   // xc ready; ps free from previous batch
            rstage_h<128, 256, 8,  true >(w1, xc, 256, ps, bias_l + 0,   bP);
            rstage_h<128, 128, 8,  false>(w2, bP, 128, ps, bias_l + 128, bQ);
            rstage_h<32,  128, 32, false>(w3, bQ, 128, ps, bias_l + 256, bX);
            rstage_h<128, 32,  8,  true >(w4, bX, 32,  ps, bias_l + 288, bP);
            rstage_h<128, 128, 8,  false>(w5, bP, 128, ps, bias_l + 416, bQ);
            rstage_h<128, 128, 8,  true >(w6, bQ, 128, ps, bias_l + 544, bP);
            // S7 partials (dot2) + prefetch next batch's xc
#pragma unroll
            for (int r = 0; r < 8; ++r) {
                const half2v xv = *reinterpret_cast<const half2v*>(&bP[r * 128 + 2 * o7]);
                ps[r * 1024 + o7 * 16 + jb7]     = __builtin_amdgcn_fdot2(xv, w7a, 0.f, false);
                ps[r * 1024 + o7 * 16 + jb7 + 8] = __builtin_amdgcn_fdot2(xv, w7b, 0.f, false);
            }
            if (rb < 3) stage_xc_h(xc, pu, hlast, n0, rb + 1);
            __syncthreads();
            if (T < 128) {
                const int r = T >> 4, j = T & 15;
                float s = bias_l[672 + j];
#pragma unroll
                for (int o2 = 0; o2 < 64; ++o2) s += ps[r * 1024 + o2 * 16 + j];
                const int trow = t0 + rb * 8 + r;
                const float yv = y_g[((size_t)b * YDIM + j) * TT + trow];
                const float d = s - yv;
                lossreg += d * d;
            }
            // loop-top barrier closes this batch
        }
    }
    __syncthreads();
#pragma unroll
    for (int off = 32; off > 0; off >>= 1) lossreg += __shfl_down(lossreg, off, 64);
    if ((T & 63) == 0) red[T >> 6] = lossreg;
    __syncthreads();
    if (T == 0) {
        float s = 0.f;
#pragma unroll
        for (int i = 0; i < 8; ++i) s += red[i];
        atomicAdd(out, s);
    }
}

__global__ void zero_out_kernel(float* o) { o[0] = 0.f; }

extern "C" void kernel_launch(void* const* d_in, const int* in_sizes, int n_in,
                              void* d_out, int out_size, void* d_ws, size_t ws_size,
                              hipStream_t stream)
{
    (void)in_sizes; (void)n_in; (void)out_size;
    const float* u    = (const float*)d_in[0];
    const float* y    = (const float*)d_in[1];
    const float* h0   = (const float*)d_in[2];
    const float* puw1 = (const float*)d_in[3];
    const float* pub1 = (const float*)d_in[4];
    const float* puw2 = (const float*)d_in[5];
    const float* pub2 = (const float*)d_in[6];
    const float* dw1  = (const float*)d_in[7];
    const float* db1  = (const float*)d_in[8];
    const float* dw2  = (const float*)d_in[9];
    const float* db2  = (const float*)d_in[10];
    const float* xw   = (const float*)d_in[11];
    const float* xbi  = (const float*)d_in[12];
    const float* pxw1 = (const float*)d_in[13];
    const float* pxb1 = (const float*)d_in[14];
    const float* pxw2 = (const float*)d_in[15];
    const float* pxb2 = (const float*)d_in[16];
    const float* mw1  = (const float*)d_in[17];
    const float* mb1  = (const float*)d_in[18];
    const float* mw2  = (const float*)d_in[19];
    const float* mb2  = (const float*)d_in[20];
    const float* gwih = (const float*)d_in[21];
    const float* gwhh = (const float*)d_in[22];

    const size_t per_sample = (size_t)TT * HH * 2 * 2;   // pu + hlast (bf16)
    int C = BB;
    while (C > 1 && (size_t)C * per_sample > ws_size) C >>= 1;
    bf16* puB = (bf16*)d_ws;
    bf16* hlB = puB + (size_t)C * TT * HH;

    zero_out_kernel<<<1, 1, 0, stream>>>((float*)d_out);
    for (int s0 = 0; s0 < BB; s0 += C) {
        phi_u_kernel<<<512, 512, 0, stream>>>(u, puw1, pub1, puw2, pub2, puB, s0, C * TT);
        gru_fused_kernel<<<C, 512, 0, stream>>>(puB, gwih, gwhh, h0, hlB, s0);
        head_kernel<<<512, 512, 0, stream>>>(puB, hlB, y,
                                             dw1, db1, dw2, db2, xw, xbi,
                                             pxw1, pxb1, pxw2, pxb2,
                                             mw1, mb1, mw2, mb2,
                                             (float*)d_out, s0, C * TT);
    }
}